// Round 13
// baseline (12486.600 us; speedup 1.0000x reference)
//
#include <hip/hip_runtime.h>
#include <cstdint>

typedef unsigned short u16;
typedef __attribute__((ext_vector_type(8))) short short8;     // 8 x bf16 (4 VGPRs)
typedef __attribute__((ext_vector_type(4))) short short4v;    // 4 x bf16 (2 VGPRs)
typedef __attribute__((ext_vector_type(4))) float f32x4;
typedef __attribute__((ext_vector_type(16))) float f32x16;

// B=64, T=512, H=512, D_IN=1024, L=2, DIRS=2

__device__ __forceinline__ u16 f2bf(float x){
  uint32_t u = __float_as_uint(x);
  u += 0x7fffu + ((u >> 16) & 1u);          // RNE
  return (u16)(u >> 16);
}
__device__ __forceinline__ float bf2f(u16 b){ return __uint_as_float(((uint32_t)b) << 16); }
__device__ __forceinline__ float sigm(float x){ return 1.f / (1.f + __expf(-x)); }
__device__ __forceinline__ float tanhx(float x){
  float xc = fminf(fmaxf(x, -30.f), 30.f);
  float e  = __expf(-2.f * xc);
  return (1.f - e) / (1.f + e);
}

// XCD-local data ops (write-once/read-once addresses ONLY -- L2-served).
// R4/R6 lessons: sc0 LOADS are L1-cacheable -> never poll with plain loads;
// atomics execute at L2+ (no L1 staleness) -> poll with atomics (R7 proven).
__device__ __forceinline__ void st8_l2(u16* p, short4v v){
  asm volatile("global_store_dwordx2 %0, %1, off sc0" :: "v"(p), "v"(v) : "memory");
}

#define CNT_STRIDE 16   // ints: one 64B sector per step counter

// ---------------- fp32 -> bf16 convert ----------------
__global__ void k_cvt(const float* __restrict__ in, u16* __restrict__ out, int n4){
  int i = blockIdx.x * blockDim.x + threadIdx.x;
  if (i >= n4) return;
  float4 v = ((const float4*)in)[i];
  ushort4 o;
  o.x = f2bf(v.x); o.y = f2bf(v.y); o.z = f2bf(v.z); o.w = f2bf(v.w);
  ((ushort4*)out)[i] = o;
}

// ---------------- input GEMM: xg = A @ W^T + bias, bf16 in, bf16 out ----------------
template<int LAYER0>
__global__ __launch_bounds__(256) void k_gemm(
    const u16* __restrict__ A, const u16* __restrict__ W,
    const float* __restrict__ bih, const float* __restrict__ bhh,
    u16* __restrict__ xg)
{
  __shared__ u16 Al[128 * 64];
  __shared__ u16 Bl[128 * 64];
  const int tid  = threadIdx.x;
  const int bm   = blockIdx.x, bn = blockIdx.y;
  const int w    = tid >> 6, lane = tid & 63;
  const int wm   = (w >> 1) * 64;
  const int wn   = (w & 1) * 64;
  f32x4 acc[4][4] = {};

  for (int kt = 0; kt < 1024; kt += 64){
    __syncthreads();
    #pragma unroll
    for (int it = 0; it < 4; ++it){
      int idx = tid + it * 256;
      int row = idx >> 3, c = idx & 7;
      size_t aoff;
      int m = bm * 128 + row;
      if (LAYER0) aoff = ((size_t)(m & 63) * 512 + (m >> 6)) * 1024;
      else        aoff = (size_t)m * 1024;
      short8 va = *(const short8*)(A + aoff + kt + c * 8);
      *(short8*)(Al + row * 64 + ((c ^ (row & 7)) * 8)) = va;
      int n = bn * 128 + row;
      short8 vb = *(const short8*)(W + (size_t)n * 1024 + kt + c * 8);
      *(short8*)(Bl + row * 64 + ((c ^ (row & 7)) * 8)) = vb;
    }
    __syncthreads();
    const int kg = lane >> 4;
    #pragma unroll
    for (int kk = 0; kk < 2; ++kk){
      short8 a[4], b[4];
      #pragma unroll
      for (int i = 0; i < 4; ++i){
        int rA = wm + i * 16 + (lane & 15);
        int cA = kk * 4 + kg;
        a[i] = *(const short8*)(Al + rA * 64 + ((cA ^ (rA & 7)) * 8));
        int rB = wn + i * 16 + (lane & 15);
        b[i] = *(const short8*)(Bl + rB * 64 + ((cA ^ (rB & 7)) * 8));
      }
      #pragma unroll
      for (int i = 0; i < 4; ++i)
        #pragma unroll
        for (int j = 0; j < 4; ++j)
          acc[i][j] = __builtin_amdgcn_mfma_f32_16x16x32_bf16(a[i], b[j], acc[i][j], 0, 0, 0);
    }
  }
  #pragma unroll
  for (int i = 0; i < 4; ++i){
    #pragma unroll
    for (int j = 0; j < 4; ++j){
      int n_g = bn * 128 + wn + j * 16 + (lane & 15);
      float bias = bih[n_g] + bhh[n_g];
      #pragma unroll
      for (int q = 0; q < 4; ++q){
        int m_g = bm * 128 + wm + i * 16 + (lane >> 4) * 4 + q;
        xg[(size_t)m_g * 4096 + n_g] = f2bf(acc[i][j][q] + bias);
      }
    }
  }
}

// ---------------- persistent LSTM recurrence (R7 structure) + phase probes ----------------
// PHASES: 4 = real kernel (512 steps). Probes run 1024 steps on scratch:
//   1 = sync skeleton only (poll + barriers + inc)
//   2 = 1 + stage 64KB + LDS write + publish/drain
//   3 = 2 + ds_read + 32 MFMA (publish depends on acc)
// Phase deltas attribute the 4.3us step to {sync, data-move, mfma-feed, gates}.
template<int LAYER, int PHASES>
__global__ __launch_bounds__(256, 1) void k_rec(
    const u16* __restrict__ whh,   // (2, 2048, 512) bf16, this layer
    const u16* __restrict__ xg,    // (32768, 4096) bf16
    u16*  __restrict__ x1,         // (32768, 1024) bf16 (probes: scratch)
    u16*  __restrict__ hexch,      // [512 t][2 dir][64][512] bf16: layer1 h exchange
    float* __restrict__ dout,      // (64, 512, 1024) fp32 final output
    int*  __restrict__ ctrl,       // election block
    int*  __restrict__ cnt)        // step counters: [dir][NSTEP][CNT_STRIDE], zeroed
{
  const int tid = threadIdx.x;
  __shared__ int sh_rank, sh_dir;

  if (tid == 0){
    uint32_t xcd;
    asm volatile("s_getreg_b32 %0, hwreg(HW_REG_XCC_ID)" : "=s"(xcd));
    xcd &= 7;
    int rank = __hip_atomic_fetch_add(ctrl + xcd * 16, 1, __ATOMIC_RELAXED, __HIP_MEMORY_SCOPE_AGENT);
    int dm;
    if (rank == 0){
      int slot = __hip_atomic_fetch_add(ctrl + 136, 1, __ATOMIC_RELAXED, __HIP_MEMORY_SCOPE_AGENT);
      dm = slot + 1;
      __hip_atomic_store(ctrl + 128 + xcd, dm, __ATOMIC_RELEASE, __HIP_MEMORY_SCOPE_AGENT);
    } else {
      do {
        dm = __hip_atomic_load(ctrl + 128 + xcd, __ATOMIC_ACQUIRE, __HIP_MEMORY_SCOPE_AGENT);
      } while (dm == 0);
    }
    sh_rank = rank; sh_dir = dm - 1;
  }
  __syncthreads();
  const int s   = sh_rank;
  const int dir = sh_dir;
  if (s >= 32 || dir >= 2) return;     // not a worker

  const int w    = tid >> 6, lane = tid & 63;
  const int wm   = (w >> 1) * 32;      // batch-row offset of this wave
  const int wn   = (w & 1) * 32;       // col offset within WG's 64 cols

  __shared__ u16  h_lds[64 * 512];     // 64 KB, 16B-chunk XOR swizzled
  __shared__ float gates_lds[4][64][16];

  // W^T slice into registers: B-frag[kk]: B[k][n], n = wn+(lane&31)
  const u16* wd = whh + (size_t)dir * (2048 * 512);
  const int  nl = wn + (lane & 31);
  const int  g_of_n = nl >> 4, j_of_n = nl & 15;
  short8 bq[32];
  {
    const size_t rbase = (size_t)(g_of_n * 512 + s * 16 + j_of_n) * 512;
    const int ko = (lane >> 5) * 8;
    #pragma unroll
    for (int kk = 0; kk < 32; ++kk)
      bq[kk] = *(const short8*)(wd + rbase + kk * 16 + ko);
  }

  float cst[4] = {0.f, 0.f, 0.f, 0.f};
  const int tstep = dir ? -1 : 1;
  const int t0    = dir ? 511 : 0;
  const int NSTEP = (PHASES == 4) ? 512 : 1024;
  int* const cntd = cnt + (size_t)dir * NSTEP * CNT_STRIDE;

  // gate-math geometry: thread owns batch gm, cols gj..gj+3
  const int gm = tid >> 2;
  const int gj = 4 * (tid & 3);

  for (int it = 0; it < NSTEP; ++it){
    const int t = t0 + tstep * (it & 511);

    // xg prefetch -- full kernel only
    ushort4 xgv[4];
    if (PHASES >= 4){
      const size_t xb0 = ((size_t)t * 64 + gm) * 4096 + (size_t)dir * 2048 + s * 16 + gj;
      #pragma unroll
      for (int g = 0; g < 4; ++g) xgv[g] = *(const ushort4*)(xg + xb0 + g * 512);
    }

    float accv[16];
    #pragma unroll
    for (int r = 0; r < 16; ++r) accv[r] = 0.f;
    short8 carry = {0,0,0,0,0,0,0,0};

    if (it > 0){
      const int tprev = t - tstep * (((it & 511) == 0) ? -511 : 1);  // probes wrap; real: t - tstep
      // ---- wait for all 32 producers of step it-1 (L2-local atomic poll) ----
      if (tid == 0){
        int* cp = cntd + (it - 1) * CNT_STRIDE;
        const int zero = 0;
        while (true){
          int old;
          asm volatile("global_atomic_add %0, %1, %2, off sc0\n\ts_waitcnt vmcnt(0)"
                       : "=v"(old) : "v"(cp), "v"(zero) : "memory");
          if (old >= 32) break;
          __builtin_amdgcn_s_sleep(1);
        }
      }
      __syncthreads();

      if (PHASES >= 2){
        // ---- stage h(t-1) (64 x 512 bf16 = 64KB) into LDS via XCD-local L2 loads ----
        const u16* hsrc;
        size_t rstride;
        if (LAYER == 0){ hsrc = x1 + ((size_t)tprev * 64) * 1024 + dir * 512; rstride = 1024; }
        else           { hsrc = hexch + ((size_t)tprev * 2 + dir) * (64 * 512); rstride = 512; }

        short8 hv[16];
        #pragma unroll
        for (int i = 0; i < 16; ++i){
          int idx = i * 256 + tid;
          int row = idx >> 6, c = idx & 63;
          const u16* src = hsrc + (size_t)row * rstride + c * 8;
          asm volatile("global_load_dwordx4 %0, %1, off sc0" : "=v"(hv[i]) : "v"(src));
        }
        asm volatile("s_waitcnt vmcnt(8)" ::: "memory");
        __builtin_amdgcn_sched_barrier(0);
        #pragma unroll
        for (int i = 0; i < 8; ++i){
          int idx = i * 256 + tid;
          int row = idx >> 6, c = idx & 63;
          *(short8*)(h_lds + row * 512 + ((c ^ (row & 7)) * 8)) = hv[i];
        }
        asm volatile("s_waitcnt vmcnt(0)" ::: "memory");
        __builtin_amdgcn_sched_barrier(0);
        #pragma unroll
        for (int i = 8; i < 16; ++i){
          int idx = i * 256 + tid;
          int row = idx >> 6, c = idx & 63;
          *(short8*)(h_lds + row * 512 + ((c ^ (row & 7)) * 8)) = hv[i];
        }
        carry = hv[15];
        __syncthreads();
      }

      if (PHASES >= 3){
        // ---- MFMA: acc[m][n] = sum_k h[m][k] * W^T[k][n] ----
        f32x16 a1 = {0,0,0,0,0,0,0,0,0,0,0,0,0,0,0,0};
        f32x16 a2 = {0,0,0,0,0,0,0,0,0,0,0,0,0,0,0,0};
        const int m  = wm + (lane & 31);
        const int cb = (lane >> 5);
        #pragma unroll
        for (int kk = 0; kk < 32; ++kk){
          int c = kk * 2 + cb;
          short8 a = *(const short8*)(h_lds + m * 512 + ((c ^ (m & 7)) * 8));
          if (kk & 1) a2 = __builtin_amdgcn_mfma_f32_32x32x16_bf16(a, bq[kk], a2, 0, 0, 0);
          else        a1 = __builtin_amdgcn_mfma_f32_32x32x16_bf16(a, bq[kk], a1, 0, 0, 0);
        }
        #pragma unroll
        for (int r = 0; r < 16; ++r) accv[r] = a1[r] + a2[r];
      }
    }

    short4v hout = {0,0,0,0};
    float hof[4] = {0.f,0.f,0.f,0.f};

    if (PHASES >= 4){
      // gates to LDS: D[m][n]: n = lane&31(+wn), m = (r&3)+8*(r>>2)+4*(lane>>5) (+wm)
      #pragma unroll
      for (int r = 0; r < 16; ++r){
        int ml = wm + (r & 3) + 8 * (r >> 2) + 4 * (lane >> 5);
        gates_lds[g_of_n][ml][j_of_n] = accv[r];
      }
      __syncthreads();
      #pragma unroll
      for (int q = 0; q < 4; ++q){
        const int j = gj + q;
        float gi = gates_lds[0][gm][j] + bf2f(xgv[0][q]);
        float gf = gates_lds[1][gm][j] + bf2f(xgv[1][q]);
        float gg = gates_lds[2][gm][j] + bf2f(xgv[2][q]);
        float go = gates_lds[3][gm][j] + bf2f(xgv[3][q]);
        float iv = sigm(gi), fv = sigm(gf), gv = tanhx(gg), ov = sigm(go);
        float c  = fv * cst[q] + iv * gv;
        cst[q]   = c;
        float h  = ov * tanhx(c);
        hof[q]   = h;
        hout[q]  = (short)f2bf(h);
      }
    } else if (PHASES == 3){
      #pragma unroll
      for (int q = 0; q < 4; ++q) hout[q] = (short)f2bf(accv[q]);   // dep on MFMA
    } else if (PHASES == 2){
      #pragma unroll
      for (int q = 0; q < 4; ++q) hout[q] = carry[q];               // dep on stage
    }

    if (PHASES >= 2){
      // publish h via XCD-local L2 stores (fresh addresses every step).
      if (LAYER == 0){
        u16* dst = x1 + ((size_t)t * 64 + gm) * 1024 + dir * 512 + s * 16 + gj;
        st8_l2(dst, hout);
        asm volatile("s_waitcnt vmcnt(0)" ::: "memory");
      } else {
        u16* dst = hexch + ((size_t)t * 2 + dir) * (64 * 512) + gm * 512 + s * 16 + gj;
        st8_l2(dst, hout);
        float4 dv = { hof[0], hof[1], hof[2], hof[3] };
        *(float4*)(dout + ((size_t)gm * 512 + t) * 1024 + dir * 512 + s * 16 + gj) = dv;
        asm volatile("s_waitcnt vmcnt(1)" ::: "memory");   // hexch ack'd; dout may fly
      }
    }
    __syncthreads();                                       // all threads' h stores ack'd
    if (tid == 0){
      int* cp = cntd + it * CNT_STRIDE;
      const int one = 1;
      asm volatile("global_atomic_add %0, %1, off" :: "v"(cp), "v"(one) : "memory");
    }
  }
}

extern "C" void kernel_launch(void* const* d_in, const int* in_sizes, int n_in,
                              void* d_out, int out_size, void* d_ws, size_t ws_size,
                              hipStream_t stream){
  (void)in_sizes; (void)n_in; (void)out_size; (void)ws_size;
  const float* seq = (const float*)d_in[0];
  const float* wih = (const float*)d_in[2];
  const float* whh = (const float*)d_in[3];
  const float* bih = (const float*)d_in[4];
  const float* bhh = (const float*)d_in[5];
  float* out = (float*)d_out;

  // control region (768 KB, memset each launch), int offsets:
  //   ctrl0 @0, ctrl1 @256, cnt0 @512 (16384), cnt1 @16896 (16384)
  //   probe ctrls @33280/33536/33792, probe cnts @34048/66816/99584 (32768 each)
  char* ws     = (char*)d_ws;
  int*  ctrl0  = (int*)ws;
  int*  ctrl1  = ctrl0 + 256;
  int*  cnt0   = ctrl0 + 512;
  int*  cnt1   = cnt0 + 16384;
  int*  ctrlP1 = ctrl0 + 33280;
  int*  ctrlP2 = ctrl0 + 33536;
  int*  ctrlP3 = ctrl0 + 33792;
  int*  cntP1  = ctrl0 + 34048;
  int*  cntP2  = ctrl0 + 66816;
  int*  cntP3  = ctrl0 + 99584;

  u16*  seqb = (u16*)(ws + 786432);                     // 33,554,432 u16 (64 MB)
  u16*  wihb = seqb + (size_t)33554432;                 //  8,388,608
  u16*  whhb = wihb + (size_t)8388608;                  //  4,194,304
  u16*  x1   = whhb + (size_t)4194304;                  // 33,554,432
  u16*  xgb  = x1   + (size_t)33554432;                 // 134,217,728
  u16*  hexb = seqb;   // layer1 t-indexed h exchange [512][2][64][512] aliases seqb
  u16*  probeX = xgb;  // probe h-exchange scratch (xgb dead after k_rec<1>; k_gemm rewrites)

  hipMemsetAsync(ctrl0, 0, 786432, stream);
  k_cvt<<<32768, 256, 0, stream>>>(seq, seqb, 8388608);
  k_cvt<<<8192,  256, 0, stream>>>(wih, wihb, 2097152);
  k_cvt<<<4096,  256, 0, stream>>>(whh, whhb, 1048576);

  dim3 gg(256, 32);
  // layer 0
  k_gemm<1><<<gg, 256, 0, stream>>>(seqb, wihb, bih, bhh, xgb);
  k_rec<0,4><<<512, 256, 0, stream>>>(whhb, xgb, x1, hexb, out, ctrl0, cnt0);
  // layer 1
  k_gemm<0><<<gg, 256, 0, stream>>>(x1, wihb + 4194304, bih + 4096, bhh + 4096, xgb);
  k_rec<1,4><<<512, 256, 0, stream>>>(whhb + 2097152, xgb, x1, hexb, out, ctrl1, cnt1);

  // ---- phase probes (scratch only; run after real work; 1024 steps each) ----
  k_rec<0,1><<<512, 256, 0, stream>>>(whhb, xgb, probeX, hexb, out, ctrlP1, cntP1);
  k_rec<0,2><<<512, 256, 0, stream>>>(whhb, xgb, probeX, hexb, out, ctrlP2, cntP2);
  k_rec<0,3><<<512, 256, 0, stream>>>(whhb, xgb, probeX, hexb, out, ctrlP3, cntP3);
}

// Round 14
// 12477.108 us; speedup vs baseline: 1.0008x; 1.0008x over previous
//
#include <hip/hip_runtime.h>
#include <cstdint>

typedef unsigned short u16;
typedef __attribute__((ext_vector_type(8))) short short8;     // 8 x bf16 (4 VGPRs)
typedef __attribute__((ext_vector_type(4))) short short4v;    // 4 x bf16 (2 VGPRs)
typedef __attribute__((ext_vector_type(4))) float f32x4;
typedef __attribute__((ext_vector_type(16))) float f32x16;

// B=64, T=512, H=512, D_IN=1024, L=2, DIRS=2

__device__ __forceinline__ u16 f2bf(float x){
  uint32_t u = __float_as_uint(x);
  u += 0x7fffu + ((u >> 16) & 1u);          // RNE
  return (u16)(u >> 16);
}
__device__ __forceinline__ float bf2f(u16 b){ return __uint_as_float(((uint32_t)b) << 16); }
__device__ __forceinline__ float sigm(float x){ return 1.f / (1.f + __expf(-x)); }
__device__ __forceinline__ float tanhx(float x){
  float xc = fminf(fmaxf(x, -30.f), 30.f);
  float e  = __expf(-2.f * xc);
  return (1.f - e) / (1.f + e);
}

// XCD-local data ops (write-once/read-once addresses ONLY -- L2-served).
// R4/R6 lessons: sc0 LOADS are L1-cacheable -> never poll with plain loads;
// atomics execute at L2+ (no L1 staleness) -> poll with atomics (R7 proven).
__device__ __forceinline__ void st8_l2(u16* p, short4v v){
  asm volatile("global_store_dwordx2 %0, %1, off sc0" :: "v"(p), "v"(v) : "memory");
}

#define CNT_STRIDE 16   // ints: one 64B sector per step counter

// ---------------- fp32 -> bf16 convert ----------------
__global__ void k_cvt(const float* __restrict__ in, u16* __restrict__ out, int n4){
  int i = blockIdx.x * blockDim.x + threadIdx.x;
  if (i >= n4) return;
  float4 v = ((const float4*)in)[i];
  ushort4 o;
  o.x = f2bf(v.x); o.y = f2bf(v.y); o.z = f2bf(v.z); o.w = f2bf(v.w);
  ((ushort4*)out)[i] = o;
}

// ---------------- input GEMM: xg = A @ W^T + bias, bf16 in, bf16 out ----------------
template<int LAYER0>
__global__ __launch_bounds__(256) void k_gemm(
    const u16* __restrict__ A, const u16* __restrict__ W,
    const float* __restrict__ bih, const float* __restrict__ bhh,
    u16* __restrict__ xg)
{
  __shared__ u16 Al[128 * 64];
  __shared__ u16 Bl[128 * 64];
  const int tid  = threadIdx.x;
  const int bm   = blockIdx.x, bn = blockIdx.y;
  const int w    = tid >> 6, lane = tid & 63;
  const int wm   = (w >> 1) * 64;
  const int wn   = (w & 1) * 64;
  f32x4 acc[4][4] = {};

  for (int kt = 0; kt < 1024; kt += 64){
    __syncthreads();
    #pragma unroll
    for (int it = 0; it < 4; ++it){
      int idx = tid + it * 256;
      int row = idx >> 3, c = idx & 7;
      size_t aoff;
      int m = bm * 128 + row;
      if (LAYER0) aoff = ((size_t)(m & 63) * 512 + (m >> 6)) * 1024;
      else        aoff = (size_t)m * 1024;
      short8 va = *(const short8*)(A + aoff + kt + c * 8);
      *(short8*)(Al + row * 64 + ((c ^ (row & 7)) * 8)) = va;
      int n = bn * 128 + row;
      short8 vb = *(const short8*)(W + (size_t)n * 1024 + kt + c * 8);
      *(short8*)(Bl + row * 64 + ((c ^ (row & 7)) * 8)) = vb;
    }
    __syncthreads();
    const int kg = lane >> 4;
    #pragma unroll
    for (int kk = 0; kk < 2; ++kk){
      short8 a[4], b[4];
      #pragma unroll
      for (int i = 0; i < 4; ++i){
        int rA = wm + i * 16 + (lane & 15);
        int cA = kk * 4 + kg;
        a[i] = *(const short8*)(Al + rA * 64 + ((cA ^ (rA & 7)) * 8));
        int rB = wn + i * 16 + (lane & 15);
        b[i] = *(const short8*)(Bl + rB * 64 + ((cA ^ (rB & 7)) * 8));
      }
      #pragma unroll
      for (int i = 0; i < 4; ++i)
        #pragma unroll
        for (int j = 0; j < 4; ++j)
          acc[i][j] = __builtin_amdgcn_mfma_f32_16x16x32_bf16(a[i], b[j], acc[i][j], 0, 0, 0);
    }
  }
  #pragma unroll
  for (int i = 0; i < 4; ++i){
    #pragma unroll
    for (int j = 0; j < 4; ++j){
      int n_g = bn * 128 + wn + j * 16 + (lane & 15);
      float bias = bih[n_g] + bhh[n_g];
      #pragma unroll
      for (int q = 0; q < 4; ++q){
        int m_g = bm * 128 + wm + i * 16 + (lane >> 4) * 4 + q;
        xg[(size_t)m_g * 4096 + n_g] = f2bf(acc[i][j][q] + bias);
      }
    }
  }
}

// ---------------- persistent LSTM recurrence (R7 structure) + phase probes ----------------
// PHASES: 4 = real kernel (512 steps). Probes run 1024 steps on scratch:
//   1 = sync skeleton only (poll + barriers + inc)
//   2 = 1 + stage 64KB + LDS write + publish/drain
//   3 = 2 + ds_read + 32 MFMA (publish depends on acc)
// Phase deltas attribute the 4.3us step to {sync, data-move, mfma-feed, gates}.
template<int LAYER, int PHASES>
__global__ __launch_bounds__(256, 1) void k_rec(
    const u16* __restrict__ whh,   // (2, 2048, 512) bf16, this layer
    const u16* __restrict__ xg,    // (32768, 4096) bf16
    u16*  __restrict__ x1,         // (32768, 1024) bf16 (probes: scratch)
    u16*  __restrict__ hexch,      // [512 t][2 dir][64][512] bf16: layer1 h exchange
    float* __restrict__ dout,      // (64, 512, 1024) fp32 final output
    int*  __restrict__ ctrl,       // election block
    int*  __restrict__ cnt)        // step counters: [dir][NSTEP][CNT_STRIDE], zeroed
{
  const int tid = threadIdx.x;
  __shared__ int sh_rank, sh_dir;

  if (tid == 0){
    uint32_t xcd;
    asm volatile("s_getreg_b32 %0, hwreg(HW_REG_XCC_ID)" : "=s"(xcd));
    xcd &= 7;
    int rank = __hip_atomic_fetch_add(ctrl + xcd * 16, 1, __ATOMIC_RELAXED, __HIP_MEMORY_SCOPE_AGENT);
    int dm;
    if (rank == 0){
      int slot = __hip_atomic_fetch_add(ctrl + 136, 1, __ATOMIC_RELAXED, __HIP_MEMORY_SCOPE_AGENT);
      dm = slot + 1;
      __hip_atomic_store(ctrl + 128 + xcd, dm, __ATOMIC_RELEASE, __HIP_MEMORY_SCOPE_AGENT);
    } else {
      do {
        dm = __hip_atomic_load(ctrl + 128 + xcd, __ATOMIC_ACQUIRE, __HIP_MEMORY_SCOPE_AGENT);
      } while (dm == 0);
    }
    sh_rank = rank; sh_dir = dm - 1;
  }
  __syncthreads();
  const int s   = sh_rank;
  const int dir = sh_dir;
  if (s >= 32 || dir >= 2) return;     // not a worker

  const int w    = tid >> 6, lane = tid & 63;
  const int wm   = (w >> 1) * 32;      // batch-row offset of this wave
  const int wn   = (w & 1) * 32;       // col offset within WG's 64 cols

  __shared__ u16  h_lds[64 * 512];     // 64 KB, 16B-chunk XOR swizzled
  __shared__ float gates_lds[4][64][16];

  // W^T slice into registers: B-frag[kk]: B[k][n], n = wn+(lane&31)
  const u16* wd = whh + (size_t)dir * (2048 * 512);
  const int  nl = wn + (lane & 31);
  const int  g_of_n = nl >> 4, j_of_n = nl & 15;
  short8 bq[32];
  {
    const size_t rbase = (size_t)(g_of_n * 512 + s * 16 + j_of_n) * 512;
    const int ko = (lane >> 5) * 8;
    #pragma unroll
    for (int kk = 0; kk < 32; ++kk)
      bq[kk] = *(const short8*)(wd + rbase + kk * 16 + ko);
  }

  float cst[4] = {0.f, 0.f, 0.f, 0.f};
  const int tstep = dir ? -1 : 1;
  const int t0    = dir ? 511 : 0;
  const int NSTEP = (PHASES == 4) ? 512 : 1024;
  int* const cntd = cnt + (size_t)dir * NSTEP * CNT_STRIDE;

  // gate-math geometry: thread owns batch gm, cols gj..gj+3
  const int gm = tid >> 2;
  const int gj = 4 * (tid & 3);

  for (int it = 0; it < NSTEP; ++it){
    const int t = t0 + tstep * (it & 511);

    // xg prefetch -- full kernel only
    ushort4 xgv[4];
    if (PHASES >= 4){
      const size_t xb0 = ((size_t)t * 64 + gm) * 4096 + (size_t)dir * 2048 + s * 16 + gj;
      #pragma unroll
      for (int g = 0; g < 4; ++g) xgv[g] = *(const ushort4*)(xg + xb0 + g * 512);
    }

    float accv[16];
    #pragma unroll
    for (int r = 0; r < 16; ++r) accv[r] = 0.f;
    short8 carry = {0,0,0,0,0,0,0,0};

    if (it > 0){
      const int tprev = t - tstep * (((it & 511) == 0) ? -511 : 1);  // probes wrap; real: t - tstep
      // ---- wait for all 32 producers of step it-1 (L2-local atomic poll) ----
      if (tid == 0){
        int* cp = cntd + (it - 1) * CNT_STRIDE;
        const int zero = 0;
        while (true){
          int old;
          asm volatile("global_atomic_add %0, %1, %2, off sc0\n\ts_waitcnt vmcnt(0)"
                       : "=v"(old) : "v"(cp), "v"(zero) : "memory");
          if (old >= 32) break;
          __builtin_amdgcn_s_sleep(1);
        }
      }
      __syncthreads();

      if (PHASES >= 2){
        // ---- stage h(t-1) (64 x 512 bf16 = 64KB) into LDS via XCD-local L2 loads ----
        const u16* hsrc;
        size_t rstride;
        if (LAYER == 0){ hsrc = x1 + ((size_t)tprev * 64) * 1024 + dir * 512; rstride = 1024; }
        else           { hsrc = hexch + ((size_t)tprev * 2 + dir) * (64 * 512); rstride = 512; }

        short8 hv[16];
        #pragma unroll
        for (int i = 0; i < 16; ++i){
          int idx = i * 256 + tid;
          int row = idx >> 6, c = idx & 63;
          const u16* src = hsrc + (size_t)row * rstride + c * 8;
          asm volatile("global_load_dwordx4 %0, %1, off sc0" : "=v"(hv[i]) : "v"(src));
        }
        asm volatile("s_waitcnt vmcnt(8)" ::: "memory");
        __builtin_amdgcn_sched_barrier(0);
        #pragma unroll
        for (int i = 0; i < 8; ++i){
          int idx = i * 256 + tid;
          int row = idx >> 6, c = idx & 63;
          *(short8*)(h_lds + row * 512 + ((c ^ (row & 7)) * 8)) = hv[i];
        }
        asm volatile("s_waitcnt vmcnt(0)" ::: "memory");
        __builtin_amdgcn_sched_barrier(0);
        #pragma unroll
        for (int i = 8; i < 16; ++i){
          int idx = i * 256 + tid;
          int row = idx >> 6, c = idx & 63;
          *(short8*)(h_lds + row * 512 + ((c ^ (row & 7)) * 8)) = hv[i];
        }
        carry = hv[15];
        __syncthreads();
      }

      if (PHASES >= 3){
        // ---- MFMA: acc[m][n] = sum_k h[m][k] * W^T[k][n] ----
        f32x16 a1 = {0,0,0,0,0,0,0,0,0,0,0,0,0,0,0,0};
        f32x16 a2 = {0,0,0,0,0,0,0,0,0,0,0,0,0,0,0,0};
        const int m  = wm + (lane & 31);
        const int cb = (lane >> 5);
        #pragma unroll
        for (int kk = 0; kk < 32; ++kk){
          int c = kk * 2 + cb;
          short8 a = *(const short8*)(h_lds + m * 512 + ((c ^ (m & 7)) * 8));
          if (kk & 1) a2 = __builtin_amdgcn_mfma_f32_32x32x16_bf16(a, bq[kk], a2, 0, 0, 0);
          else        a1 = __builtin_amdgcn_mfma_f32_32x32x16_bf16(a, bq[kk], a1, 0, 0, 0);
        }
        #pragma unroll
        for (int r = 0; r < 16; ++r) accv[r] = a1[r] + a2[r];
      }
    }

    short4v hout = {0,0,0,0};
    float hof[4] = {0.f,0.f,0.f,0.f};

    if (PHASES >= 4){
      // gates to LDS: D[m][n]: n = lane&31(+wn), m = (r&3)+8*(r>>2)+4*(lane>>5) (+wm)
      #pragma unroll
      for (int r = 0; r < 16; ++r){
        int ml = wm + (r & 3) + 8 * (r >> 2) + 4 * (lane >> 5);
        gates_lds[g_of_n][ml][j_of_n] = accv[r];
      }
      __syncthreads();
      #pragma unroll
      for (int q = 0; q < 4; ++q){
        const int j = gj + q;
        float gi = gates_lds[0][gm][j] + bf2f(xgv[0][q]);
        float gf = gates_lds[1][gm][j] + bf2f(xgv[1][q]);
        float gg = gates_lds[2][gm][j] + bf2f(xgv[2][q]);
        float go = gates_lds[3][gm][j] + bf2f(xgv[3][q]);
        float iv = sigm(gi), fv = sigm(gf), gv = tanhx(gg), ov = sigm(go);
        float c  = fv * cst[q] + iv * gv;
        cst[q]   = c;
        float h  = ov * tanhx(c);
        hof[q]   = h;
        hout[q]  = (short)f2bf(h);
      }
    } else if (PHASES == 3){
      #pragma unroll
      for (int q = 0; q < 4; ++q) hout[q] = (short)f2bf(accv[q]);   // dep on MFMA
    } else if (PHASES == 2){
      #pragma unroll
      for (int q = 0; q < 4; ++q) hout[q] = carry[q];               // dep on stage
    }

    if (PHASES >= 2){
      // publish h via XCD-local L2 stores (fresh addresses every step).
      if (LAYER == 0){
        u16* dst = x1 + ((size_t)t * 64 + gm) * 1024 + dir * 512 + s * 16 + gj;
        st8_l2(dst, hout);
        asm volatile("s_waitcnt vmcnt(0)" ::: "memory");
      } else {
        u16* dst = hexch + ((size_t)t * 2 + dir) * (64 * 512) + gm * 512 + s * 16 + gj;
        st8_l2(dst, hout);
        float4 dv = { hof[0], hof[1], hof[2], hof[3] };
        *(float4*)(dout + ((size_t)gm * 512 + t) * 1024 + dir * 512 + s * 16 + gj) = dv;
        asm volatile("s_waitcnt vmcnt(1)" ::: "memory");   // hexch ack'd; dout may fly
      }
    }
    __syncthreads();                                       // all threads' h stores ack'd
    if (tid == 0){
      int* cp = cntd + it * CNT_STRIDE;
      const int one = 1;
      asm volatile("global_atomic_add %0, %1, off" :: "v"(cp), "v"(one) : "memory");
    }
  }
}

extern "C" void kernel_launch(void* const* d_in, const int* in_sizes, int n_in,
                              void* d_out, int out_size, void* d_ws, size_t ws_size,
                              hipStream_t stream){
  (void)in_sizes; (void)n_in; (void)out_size; (void)ws_size;
  const float* seq = (const float*)d_in[0];
  const float* wih = (const float*)d_in[2];
  const float* whh = (const float*)d_in[3];
  const float* bih = (const float*)d_in[4];
  const float* bhh = (const float*)d_in[5];
  float* out = (float*)d_out;

  // control region (768 KB, memset each launch), int offsets:
  //   ctrl0 @0, ctrl1 @256, cnt0 @512 (16384), cnt1 @16896 (16384)
  //   probe ctrls @33280/33536/33792, probe cnts @34048/66816/99584 (32768 each)
  char* ws     = (char*)d_ws;
  int*  ctrl0  = (int*)ws;
  int*  ctrl1  = ctrl0 + 256;
  int*  cnt0   = ctrl0 + 512;
  int*  cnt1   = cnt0 + 16384;
  int*  ctrlP1 = ctrl0 + 33280;
  int*  ctrlP2 = ctrl0 + 33536;
  int*  ctrlP3 = ctrl0 + 33792;
  int*  cntP1  = ctrl0 + 34048;
  int*  cntP2  = ctrl0 + 66816;
  int*  cntP3  = ctrl0 + 99584;

  u16*  seqb = (u16*)(ws + 786432);                     // 33,554,432 u16 (64 MB)
  u16*  wihb = seqb + (size_t)33554432;                 //  8,388,608
  u16*  whhb = wihb + (size_t)8388608;                  //  4,194,304
  u16*  x1   = whhb + (size_t)4194304;                  // 33,554,432
  u16*  xgb  = x1   + (size_t)33554432;                 // 134,217,728
  u16*  hexb = seqb;   // layer1 t-indexed h exchange [512][2][64][512] aliases seqb
  u16*  probeX = xgb;  // probe h-exchange scratch (xgb dead after k_rec<1>; k_gemm rewrites)

  hipMemsetAsync(ctrl0, 0, 786432, stream);
  k_cvt<<<32768, 256, 0, stream>>>(seq, seqb, 8388608);
  k_cvt<<<8192,  256, 0, stream>>>(wih, wihb, 2097152);
  k_cvt<<<4096,  256, 0, stream>>>(whh, whhb, 1048576);

  dim3 gg(256, 32);
  // layer 0
  k_gemm<1><<<gg, 256, 0, stream>>>(seqb, wihb, bih, bhh, xgb);
  k_rec<0,4><<<512, 256, 0, stream>>>(whhb, xgb, x1, hexb, out, ctrl0, cnt0);
  // layer 1
  k_gemm<0><<<gg, 256, 0, stream>>>(x1, wihb + 4194304, bih + 4096, bhh + 4096, xgb);
  k_rec<1,4><<<512, 256, 0, stream>>>(whhb + 2097152, xgb, x1, hexb, out, ctrl1, cnt1);

  // ---- phase probes (scratch only; run after real work; 1024 steps each) ----
  k_rec<0,1><<<512, 256, 0, stream>>>(whhb, xgb, probeX, hexb, out, ctrlP1, cntP1);
  k_rec<0,2><<<512, 256, 0, stream>>>(whhb, xgb, probeX, hexb, out, ctrlP2, cntP2);
  k_rec<0,3><<<512, 256, 0, stream>>>(whhb, xgb, probeX, hexb, out, ctrlP3, cntP3);
}

// Round 15
// 5837.310 us; speedup vs baseline: 2.1391x; 2.1375x over previous
//
#include <hip/hip_runtime.h>
#include <cstdint>

typedef unsigned short u16;
typedef __attribute__((ext_vector_type(8))) short short8;     // 8 x bf16 (4 VGPRs)
typedef __attribute__((ext_vector_type(4))) short short4v;    // 4 x bf16 (2 VGPRs)
typedef __attribute__((ext_vector_type(4))) float f32x4;
typedef __attribute__((ext_vector_type(16))) float f32x16;

// B=64, T=512, H=512, D_IN=1024, L=2, DIRS=2

__device__ __forceinline__ u16 f2bf(float x){
  uint32_t u = __float_as_uint(x);
  u += 0x7fffu + ((u >> 16) & 1u);          // RNE
  return (u16)(u >> 16);
}
__device__ __forceinline__ float bf2f(u16 b){ return __uint_as_float(((uint32_t)b) << 16); }
__device__ __forceinline__ float sigm(float x){ return 1.f / (1.f + __expf(-x)); }
__device__ __forceinline__ float tanhx(float x){
  float xc = fminf(fmaxf(x, -30.f), 30.f);
  float e  = __expf(-2.f * xc);
  return (1.f - e) / (1.f + e);
}

// XCD-local coherent store (bypass L1, lands in the XCD's L2).
// R4/R6 lessons: sc0 LOADS are L1-cacheable -> never poll with plain loads;
// atomics execute at L2+ (no L1 staleness) -> poll with atomics (R7 proven).
__device__ __forceinline__ void st8_l2(u16* p, short4v v){
  asm volatile("global_store_dwordx2 %0, %1, off sc0" :: "v"(p), "v"(v) : "memory");
}

#define CNT_STRIDE 16   // ints: one 64B sector per step counter

// ---------------- fp32 -> bf16 convert ----------------
__global__ void k_cvt(const float* __restrict__ in, u16* __restrict__ out, int n4){
  int i = blockIdx.x * blockDim.x + threadIdx.x;
  if (i >= n4) return;
  float4 v = ((const float4*)in)[i];
  ushort4 o;
  o.x = f2bf(v.x); o.y = f2bf(v.y); o.z = f2bf(v.z); o.w = f2bf(v.w);
  ((ushort4*)out)[i] = o;
}

// ---------------- input GEMM: xg = A @ W^T + bias, bf16 in, bf16 out ----------------
template<int LAYER0>
__global__ __launch_bounds__(256) void k_gemm(
    const u16* __restrict__ A, const u16* __restrict__ W,
    const float* __restrict__ bih, const float* __restrict__ bhh,
    u16* __restrict__ xg)
{
  __shared__ u16 Al[128 * 64];
  __shared__ u16 Bl[128 * 64];
  const int tid  = threadIdx.x;
  const int bm   = blockIdx.x, bn = blockIdx.y;
  const int w    = tid >> 6, lane = tid & 63;
  const int wm   = (w >> 1) * 64;
  const int wn   = (w & 1) * 64;
  f32x4 acc[4][4] = {};

  for (int kt = 0; kt < 1024; kt += 64){
    __syncthreads();
    #pragma unroll
    for (int it = 0; it < 4; ++it){
      int idx = tid + it * 256;
      int row = idx >> 3, c = idx & 7;
      size_t aoff;
      int m = bm * 128 + row;
      if (LAYER0) aoff = ((size_t)(m & 63) * 512 + (m >> 6)) * 1024;
      else        aoff = (size_t)m * 1024;
      short8 va = *(const short8*)(A + aoff + kt + c * 8);
      *(short8*)(Al + row * 64 + ((c ^ (row & 7)) * 8)) = va;
      int n = bn * 128 + row;
      short8 vb = *(const short8*)(W + (size_t)n * 1024 + kt + c * 8);
      *(short8*)(Bl + row * 64 + ((c ^ (row & 7)) * 8)) = vb;
    }
    __syncthreads();
    const int kg = lane >> 4;
    #pragma unroll
    for (int kk = 0; kk < 2; ++kk){
      short8 a[4], b[4];
      #pragma unroll
      for (int i = 0; i < 4; ++i){
        int rA = wm + i * 16 + (lane & 15);
        int cA = kk * 4 + kg;
        a[i] = *(const short8*)(Al + rA * 64 + ((cA ^ (rA & 7)) * 8));
        int rB = wn + i * 16 + (lane & 15);
        b[i] = *(const short8*)(Bl + rB * 64 + ((cA ^ (rB & 7)) * 8));
      }
      #pragma unroll
      for (int i = 0; i < 4; ++i)
        #pragma unroll
        for (int j = 0; j < 4; ++j)
          acc[i][j] = __builtin_amdgcn_mfma_f32_16x16x32_bf16(a[i], b[j], acc[i][j], 0, 0, 0);
    }
  }
  #pragma unroll
  for (int i = 0; i < 4; ++i){
    #pragma unroll
    for (int j = 0; j < 4; ++j){
      int n_g = bn * 128 + wn + j * 16 + (lane & 15);
      float bias = bih[n_g] + bhh[n_g];
      #pragma unroll
      for (int q = 0; q < 4; ++q){
        int m_g = bm * 128 + wm + i * 16 + (lane >> 4) * 4 + q;
        xg[(size_t)m_g * 4096 + n_g] = f2bf(acc[i][j][q] + bias);
      }
    }
  }
}

// ---------------- persistent LSTM recurrence: packed-h direct consume ----------------
// Election (R3), atomic-counter sync (R7). NEW (R15): h is exchanged in MFMA-A-fragment
// order hpack[t][dir][kk 0..31][cb 0..1][m 0..63][8 bf16] (64KB per t,dir). Consumers
// feed MFMA straight from L2 via a 12-slot ring pipeline (counted vmcnt; xg loads are
// the oldest in-queue so the counts remain exact/conservative). No h LDS staging.
template<int LAYER>
__global__ __launch_bounds__(256, 1) void k_rec(
    const u16* __restrict__ whh,   // (2, 2048, 512) bf16, this layer
    const u16* __restrict__ xg,    // (32768, 4096) bf16
    u16*  __restrict__ x1,         // (32768, 1024) bf16 row-major (layer0 out for gemm)
    u16*  __restrict__ hpk,        // [512 t][2 dir][32768] bf16 packed h exchange
    float* __restrict__ dout,      // (64, 512, 1024) fp32 final output
    int*  __restrict__ ctrl,       // election block: cnt[8*16], dirmap@128..135, slot@136
    int*  __restrict__ cnt)        // step counters: [dir][512][CNT_STRIDE], zeroed
{
  const int tid = threadIdx.x;
  __shared__ int sh_rank, sh_dir;

  if (tid == 0){
    uint32_t xcd;
    asm volatile("s_getreg_b32 %0, hwreg(HW_REG_XCC_ID)" : "=s"(xcd));
    xcd &= 7;
    int rank = __hip_atomic_fetch_add(ctrl + xcd * 16, 1, __ATOMIC_RELAXED, __HIP_MEMORY_SCOPE_AGENT);
    int dm;
    if (rank == 0){
      int slot = __hip_atomic_fetch_add(ctrl + 136, 1, __ATOMIC_RELAXED, __HIP_MEMORY_SCOPE_AGENT);
      dm = slot + 1;
      __hip_atomic_store(ctrl + 128 + xcd, dm, __ATOMIC_RELEASE, __HIP_MEMORY_SCOPE_AGENT);
    } else {
      do {
        dm = __hip_atomic_load(ctrl + 128 + xcd, __ATOMIC_ACQUIRE, __HIP_MEMORY_SCOPE_AGENT);
      } while (dm == 0);
    }
    sh_rank = rank; sh_dir = dm - 1;
  }
  __syncthreads();
  const int s   = sh_rank;
  const int dir = sh_dir;
  if (s >= 32 || dir >= 2) return;     // not a worker

  const int w    = tid >> 6, lane = tid & 63;
  const int wm   = (w >> 1) * 32;      // batch-row offset of this wave
  const int wn   = (w & 1) * 32;       // col offset within WG's 64 cols
  const int lm   = wm + (lane & 31);   // A-frag row of this lane
  const int lcb  = lane >> 5;          // A-frag k-half of this lane

  __shared__ float gates_lds[4][64][16];   // 16 KB (h_lds deleted)

  // W^T slice into registers: B-frag[kk]: B[k][n], n = wn+(lane&31)
  const u16* wd = whh + (size_t)dir * (2048 * 512);
  const int  nl = wn + (lane & 31);
  const int  g_of_n = nl >> 4, j_of_n = nl & 15;
  short8 bq[32];
  {
    const size_t rbase = (size_t)(g_of_n * 512 + s * 16 + j_of_n) * 512;
    const int ko = (lane >> 5) * 8;
    #pragma unroll
    for (int kk = 0; kk < 32; ++kk)
      bq[kk] = *(const short8*)(wd + rbase + kk * 16 + ko);
  }

  float cst[4] = {0.f, 0.f, 0.f, 0.f};
  const int tstep = dir ? -1 : 1;
  const int t0    = dir ? 511 : 0;
  int* const cntd = cnt + (size_t)dir * 512 * CNT_STRIDE;

  // gate-math geometry: thread owns batch gm, cols gj..gj+3
  const int gm = tid >> 2;
  const int gj = 4 * (tid & 3);
  const int pcb = gj >> 3;             // packed cb of this thread's 4 cols
  const int pe  = gj & 7;              // packed element offset

  for (int it = 0; it < 512; ++it){
    const int t = t0 + tstep * it;

    // xg prefetch (plain cached loads; OLDEST in vmcnt queue -- cannot sink past the
    // "memory"-clobbered poll/waitcnt asms or the __syncthreads below)
    const size_t xb0 = ((size_t)t * 64 + gm) * 4096 + (size_t)dir * 2048 + s * 16 + gj;
    ushort4 xgv[4];
    #pragma unroll
    for (int g = 0; g < 4; ++g) xgv[g] = *(const ushort4*)(xg + xb0 + g * 512);

    float accv[16];
    #pragma unroll
    for (int r = 0; r < 16; ++r) accv[r] = 0.f;

    if (it > 0){
      const int tprev = t - tstep;
      // ---- wait for all 32 producers of step it-1 (L2-local atomic poll) ----
      if (tid == 0){
        int* cp = cntd + (it - 1) * CNT_STRIDE;
        const int zero = 0;
        while (true){
          int old;
          asm volatile("global_atomic_add %0, %1, %2, off sc0\n\ts_waitcnt vmcnt(0)"
                       : "=v"(old) : "v"(cp), "v"(zero) : "memory");
          if (old >= 32) break;
          __builtin_amdgcn_s_sleep(1);
        }
      }
      __syncthreads();

      // ---- A-frags straight from XCD L2 (packed layout, coalesced), ring pipeline ----
      // chunk kk load: lane reads 16B at ((kk*2+lcb)*64+lm)*8 -- lanes contiguous.
      // Plain loads: addresses fresh-per-step (L1 inv'd at dispatch start; producer
      // stores were sc0 write-through, never our-L1-resident); wave pairs sharing an
      // m-half dedup in L1 -> ~2MB/step/dir from L2.
      const u16* hb = hpk + ((size_t)tprev * 2 + dir) * 32768;
      short8 hv[12];
      #pragma unroll
      for (int p = 0; p < 8; ++p){
        const u16* src = hb + (size_t)((p * 2 + lcb) * 64 + lm) * 8;
        asm volatile("global_load_dwordx4 %0, %1, off" : "=v"(hv[p]) : "v"(src));
      }
      f32x16 a1 = {0,0,0,0,0,0,0,0,0,0,0,0,0,0,0,0};
      f32x16 a2 = {0,0,0,0,0,0,0,0,0,0,0,0,0,0,0,0};
      #pragma unroll
      for (int g8 = 0; g8 < 8; ++g8){
        if (g8 <= 5){
          // issue 4 ahead into slots consumed LAST group (WAR distance >= 1 group)
          #pragma unroll
          for (int p = 0; p < 4; ++p){
            int q = 8 + g8 * 4 + p;
            const u16* src = hb + (size_t)((q * 2 + lcb) * 64 + lm) * 8;
            asm volatile("global_load_dwordx4 %0, %1, off" : "=v"(hv[q % 12]) : "v"(src));
          }
          asm volatile("s_waitcnt vmcnt(8)" ::: "memory");
        } else if (g8 == 6){
          asm volatile("s_waitcnt vmcnt(4)" ::: "memory");
        } else {
          asm volatile("s_waitcnt vmcnt(0)" ::: "memory");
        }
        __builtin_amdgcn_sched_barrier(0);
        #pragma unroll
        for (int p = 0; p < 4; ++p){
          int kk = g8 * 4 + p;
          short8 a = hv[kk % 12];
          if (kk & 1) a2 = __builtin_amdgcn_mfma_f32_32x32x16_bf16(a, bq[kk], a2, 0, 0, 0);
          else        a1 = __builtin_amdgcn_mfma_f32_32x32x16_bf16(a, bq[kk], a1, 0, 0, 0);
        }
      }
      #pragma unroll
      for (int r = 0; r < 16; ++r) accv[r] = a1[r] + a2[r];
    }

    // gates to LDS: D[m][n]: n = lane&31(+wn), m = (r&3)+8*(r>>2)+4*(lane>>5) (+wm)
    #pragma unroll
    for (int r = 0; r < 16; ++r){
      int ml = wm + (r & 3) + 8 * (r >> 2) + 4 * (lane >> 5);
      gates_lds[g_of_n][ml][j_of_n] = accv[r];
    }
    __syncthreads();

    // gate math + state update
    short4v hout;
    float hof[4];
    #pragma unroll
    for (int q = 0; q < 4; ++q){
      const int j = gj + q;
      float gi = gates_lds[0][gm][j] + bf2f(xgv[0][q]);
      float gf = gates_lds[1][gm][j] + bf2f(xgv[1][q]);
      float gg = gates_lds[2][gm][j] + bf2f(xgv[2][q]);
      float go = gates_lds[3][gm][j] + bf2f(xgv[3][q]);
      float iv = sigm(gi), fv = sigm(gf), gv = tanhx(gg), ov = sigm(go);
      float c  = fv * cst[q] + iv * gv;
      cst[q]   = c;
      float h  = ov * tanhx(c);
      hof[q]   = h;
      hout[q]  = (short)f2bf(h);
    }

    // publish: packed store FIRST (sc0, drained), secondary store may fly to kernel end
    u16* pk = hpk + ((size_t)t * 2 + dir) * 32768
                  + (size_t)((s * 2 + pcb) * 64 + gm) * 8 + pe;
    st8_l2(pk, hout);
    if (LAYER == 0){
      *(short4v*)(x1 + ((size_t)t * 64 + gm) * 1024 + dir * 512 + s * 16 + gj) = hout;
    } else {
      float4 dv = { hof[0], hof[1], hof[2], hof[3] };
      *(float4*)(dout + ((size_t)gm * 512 + t) * 1024 + dir * 512 + s * 16 + gj) = dv;
    }
    asm volatile("s_waitcnt vmcnt(1)" ::: "memory");   // packed store ack'd in L2
    __syncthreads();                                   // all threads' packed stores ack'd
    if (tid == 0){
      int* cp = cntd + it * CNT_STRIDE;
      const int one = 1;
      asm volatile("global_atomic_add %0, %1, off" :: "v"(cp), "v"(one) : "memory");
    }
  }
}

extern "C" void kernel_launch(void* const* d_in, const int* in_sizes, int n_in,
                              void* d_out, int out_size, void* d_ws, size_t ws_size,
                              hipStream_t stream){
  (void)in_sizes; (void)n_in; (void)out_size; (void)ws_size;
  const float* seq = (const float*)d_in[0];
  const float* wih = (const float*)d_in[2];
  const float* whh = (const float*)d_in[3];
  const float* bih = (const float*)d_in[4];
  const float* bhh = (const float*)d_in[5];
  float* out = (float*)d_out;

  // control block (256 KB, memset each launch):
  //   ctrl0 [0..255], ctrl1 [256..511], cnt0 @512 (16384 ints), cnt1 @16896 (16384 ints)
  char* ws    = (char*)d_ws;
  int*  ctrl0 = (int*)ws;
  int*  ctrl1 = ctrl0 + 256;
  int*  cnt0  = ctrl0 + 512;
  int*  cnt1  = cnt0 + 16384;

  u16*  seqb = (u16*)(ws + 262144);                     // 33,554,432 u16 (64 MB)
  u16*  wihb = seqb + (size_t)33554432;                 //  8,388,608
  u16*  whhb = wihb + (size_t)8388608;                  //  4,194,304
  u16*  x1   = whhb + (size_t)4194304;                  // 33,554,432
  u16*  xgb  = x1   + (size_t)33554432;                 // 134,217,728
  u16*  hpk  = seqb;   // packed h exchange [512][2][32768] aliases seqb (dead after
                       // k_gemm<1>; k_rec<0> and k_rec<1> reuse it sequentially --
                       // dispatch-end L2 writeback makes cross-dispatch reuse safe)

  hipMemsetAsync(ctrl0, 0, 262144, stream);
  k_cvt<<<32768, 256, 0, stream>>>(seq, seqb, 8388608);
  k_cvt<<<8192,  256, 0, stream>>>(wih, wihb, 2097152);
  k_cvt<<<4096,  256, 0, stream>>>(whh, whhb, 1048576);

  dim3 gg(256, 32);
  // layer 0
  k_gemm<1><<<gg, 256, 0, stream>>>(seqb, wihb, bih, bhh, xgb);
  k_rec<0><<<512, 256, 0, stream>>>(whhb, xgb, x1, hpk, out, ctrl0, cnt0);
  // layer 1
  k_gemm<0><<<gg, 256, 0, stream>>>(x1, wihb + 4194304, bih + 4096, bhh + 4096, xgb);
  k_rec<1><<<512, 256, 0, stream>>>(whhb + 2097152, xgb, x1, hpk, out, ctrl1, cnt1);
}

// Round 16
// 5041.283 us; speedup vs baseline: 2.4769x; 1.1579x over previous
//
#include <hip/hip_runtime.h>
#include <cstdint>

typedef unsigned short u16;
typedef __attribute__((ext_vector_type(8))) short short8;     // 8 x bf16 (4 VGPRs)
typedef __attribute__((ext_vector_type(4))) short short4v;    // 4 x bf16 (2 VGPRs)
typedef __attribute__((ext_vector_type(4))) float f32x4;
typedef __attribute__((ext_vector_type(16))) float f32x16;

// B=64, T=512, H=512, D_IN=1024, L=2, DIRS=2

__device__ __forceinline__ u16 f2bf(float x){
  uint32_t u = __float_as_uint(x);
  u += 0x7fffu + ((u >> 16) & 1u);          // RNE
  return (u16)(u >> 16);
}
__device__ __forceinline__ float bf2f(u16 b){ return __uint_as_float(((uint32_t)b) << 16); }
__device__ __forceinline__ float sigm(float x){ return 1.f / (1.f + __expf(-x)); }
__device__ __forceinline__ float tanhx(float x){
  float xc = fminf(fmaxf(x, -30.f), 30.f);
  float e  = __expf(-2.f * xc);
  return (1.f - e) / (1.f + e);
}

// XCD-local coherent store (bypass L1, lands in the XCD's L2).
// R4/R6 lessons: sc0 LOADS are L1-cacheable -> never poll with plain loads;
// atomics execute at L2+ (no L1 staleness) -> poll with atomics (R7 proven).
__device__ __forceinline__ void st8_l2(u16* p, short4v v){
  asm volatile("global_store_dwordx2 %0, %1, off sc0" :: "v"(p), "v"(v) : "memory");
}

#define CNT_STRIDE 16   // ints: one 64B sector per step counter

// ---------------- fp32 -> bf16 convert ----------------
__global__ void k_cvt(const float* __restrict__ in, u16* __restrict__ out, int n4){
  int i = blockIdx.x * blockDim.x + threadIdx.x;
  if (i >= n4) return;
  float4 v = ((const float4*)in)[i];
  ushort4 o;
  o.x = f2bf(v.x); o.y = f2bf(v.y); o.z = f2bf(v.z); o.w = f2bf(v.w);
  ((ushort4*)out)[i] = o;
}

// ---------------- input GEMM: xg = A @ W^T + bias, bf16 in, bf16 out ----------------
template<int LAYER0>
__global__ __launch_bounds__(256) void k_gemm(
    const u16* __restrict__ A, const u16* __restrict__ W,
    const float* __restrict__ bih, const float* __restrict__ bhh,
    u16* __restrict__ xg)
{
  __shared__ u16 Al[128 * 64];
  __shared__ u16 Bl[128 * 64];
  const int tid  = threadIdx.x;
  const int bm   = blockIdx.x, bn = blockIdx.y;
  const int w    = tid >> 6, lane = tid & 63;
  const int wm   = (w >> 1) * 64;
  const int wn   = (w & 1) * 64;
  f32x4 acc[4][4] = {};

  for (int kt = 0; kt < 1024; kt += 64){
    __syncthreads();
    #pragma unroll
    for (int it = 0; it < 4; ++it){
      int idx = tid + it * 256;
      int row = idx >> 3, c = idx & 7;
      size_t aoff;
      int m = bm * 128 + row;
      if (LAYER0) aoff = ((size_t)(m & 63) * 512 + (m >> 6)) * 1024;
      else        aoff = (size_t)m * 1024;
      short8 va = *(const short8*)(A + aoff + kt + c * 8);
      *(short8*)(Al + row * 64 + ((c ^ (row & 7)) * 8)) = va;
      int n = bn * 128 + row;
      short8 vb = *(const short8*)(W + (size_t)n * 1024 + kt + c * 8);
      *(short8*)(Bl + row * 64 + ((c ^ (row & 7)) * 8)) = vb;
    }
    __syncthreads();
    const int kg = lane >> 4;
    #pragma unroll
    for (int kk = 0; kk < 2; ++kk){
      short8 a[4], b[4];
      #pragma unroll
      for (int i = 0; i < 4; ++i){
        int rA = wm + i * 16 + (lane & 15);
        int cA = kk * 4 + kg;
        a[i] = *(const short8*)(Al + rA * 64 + ((cA ^ (rA & 7)) * 8));
        int rB = wn + i * 16 + (lane & 15);
        b[i] = *(const short8*)(Bl + rB * 64 + ((cA ^ (rB & 7)) * 8));
      }
      #pragma unroll
      for (int i = 0; i < 4; ++i)
        #pragma unroll
        for (int j = 0; j < 4; ++j)
          acc[i][j] = __builtin_amdgcn_mfma_f32_16x16x32_bf16(a[i], b[j], acc[i][j], 0, 0, 0);
    }
  }
  #pragma unroll
  for (int i = 0; i < 4; ++i){
    #pragma unroll
    for (int j = 0; j < 4; ++j){
      int n_g = bn * 128 + wn + j * 16 + (lane & 15);
      float bias = bih[n_g] + bhh[n_g];
      #pragma unroll
      for (int q = 0; q < 4; ++q){
        int m_g = bm * 128 + wm + i * 16 + (lane >> 4) * 4 + q;
        xg[(size_t)m_g * 4096 + n_g] = f2bf(acc[i][j][q] + bias);
      }
    }
  }
}

// ---------------- persistent LSTM recurrence (R7 base + staggered staging) ----------------
// Election (R3), atomic-counter sync (R7), LDS staging (best structure).
// R16: each WG walks the 16 staging chunks rotated by its rank s, so the 32 WGs
// are spread across the 4096 16B-chunks instead of convoying on the same L2 lines
// (L2 has no multicast -- identical walk order serializes 32 requests per line).
template<int LAYER>
__global__ __launch_bounds__(256, 1) void k_rec(
    const u16* __restrict__ whh,   // (2, 2048, 512) bf16, this layer
    const u16* __restrict__ xg,    // (32768, 4096) bf16
    u16*  __restrict__ x1,         // (32768, 1024) bf16: layer0 output + layer0 h exchange
    u16*  __restrict__ hexch,      // [512 t][2 dir][64][512] bf16: layer1 h exchange
    float* __restrict__ dout,      // (64, 512, 1024) fp32 final output
    int*  __restrict__ ctrl,       // election block: cnt[8*16], dirmap@128..135, slot@136
    int*  __restrict__ cnt)        // step counters: [dir][512][CNT_STRIDE], zeroed
{
  const int tid = threadIdx.x;
  __shared__ int sh_rank, sh_dir;

  if (tid == 0){
    uint32_t xcd;
    asm volatile("s_getreg_b32 %0, hwreg(HW_REG_XCC_ID)" : "=s"(xcd));
    xcd &= 7;
    int rank = __hip_atomic_fetch_add(ctrl + xcd * 16, 1, __ATOMIC_RELAXED, __HIP_MEMORY_SCOPE_AGENT);
    int dm;
    if (rank == 0){
      int slot = __hip_atomic_fetch_add(ctrl + 136, 1, __ATOMIC_RELAXED, __HIP_MEMORY_SCOPE_AGENT);
      dm = slot + 1;
      __hip_atomic_store(ctrl + 128 + xcd, dm, __ATOMIC_RELEASE, __HIP_MEMORY_SCOPE_AGENT);
    } else {
      do {
        dm = __hip_atomic_load(ctrl + 128 + xcd, __ATOMIC_ACQUIRE, __HIP_MEMORY_SCOPE_AGENT);
      } while (dm == 0);
    }
    sh_rank = rank; sh_dir = dm - 1;
  }
  __syncthreads();
  const int s   = sh_rank;
  const int dir = sh_dir;
  if (s >= 32 || dir >= 2) return;     // not a worker

  const int w    = tid >> 6, lane = tid & 63;
  const int wm   = (w >> 1) * 32;      // batch-row offset of this wave
  const int wn   = (w & 1) * 32;       // col offset within WG's 64 cols

  __shared__ u16  h_lds[64 * 512];     // 64 KB, 16B-chunk XOR swizzled
  __shared__ float gates_lds[4][64][16];

  // W^T slice into registers: B-frag[kk]: B[k][n], n = wn+(lane&31)
  const u16* wd = whh + (size_t)dir * (2048 * 512);
  const int  nl = wn + (lane & 31);
  const int  g_of_n = nl >> 4, j_of_n = nl & 15;
  short8 bq[32];
  {
    const size_t rbase = (size_t)(g_of_n * 512 + s * 16 + j_of_n) * 512;
    const int ko = (lane >> 5) * 8;
    #pragma unroll
    for (int kk = 0; kk < 32; ++kk)
      bq[kk] = *(const short8*)(wd + rbase + kk * 16 + ko);
  }

  float cst[4] = {0.f, 0.f, 0.f, 0.f};
  const int tstep = dir ? -1 : 1;
  const int t0    = dir ? 511 : 0;
  int* const cntd = cnt + (size_t)dir * 512 * CNT_STRIDE;

  // gate-math geometry: thread owns batch gm, cols gj..gj+3
  const int gm = tid >> 2;
  const int gj = 4 * (tid & 3);

  for (int it = 0; it < 512; ++it){
    const int t = t0 + tstep * it;

    // xg prefetch (plain cached loads; drained by the poll's first vmcnt(0) --
    // HBM latency hides under the poll observe window)
    const size_t xb0 = ((size_t)t * 64 + gm) * 4096 + (size_t)dir * 2048 + s * 16 + gj;
    ushort4 xgv[4];
    #pragma unroll
    for (int g = 0; g < 4; ++g) xgv[g] = *(const ushort4*)(xg + xb0 + g * 512);

    float accv[16];
    #pragma unroll
    for (int r = 0; r < 16; ++r) accv[r] = 0.f;

    if (it > 0){
      const int tprev = t - tstep;
      // ---- wait for all 32 producers of step it-1 (L2-local atomic poll) ----
      if (tid == 0){
        int* cp = cntd + (it - 1) * CNT_STRIDE;
        const int zero = 0;
        while (true){
          int old;
          asm volatile("global_atomic_add %0, %1, %2, off sc0\n\ts_waitcnt vmcnt(0)"
                       : "=v"(old) : "v"(cp), "v"(zero) : "memory");
          if (old >= 32) break;
          __builtin_amdgcn_s_sleep(1);
        }
      }
      __syncthreads();

      // ---- stage h(t-1) (64KB) into LDS, chunk order ROTATED by WG rank ----
      const u16* hsrc;
      size_t rstride;
      if (LAYER == 0){ hsrc = x1 + ((size_t)tprev * 64) * 1024 + dir * 512; rstride = 1024; }
      else           { hsrc = hexch + ((size_t)tprev * 2 + dir) * (64 * 512); rstride = 512; }

      short8 hv[16];
      #pragma unroll
      for (int i = 0; i < 16; ++i){
        int ii  = (i + s) & 15;            // staggered walk
        int idx = ii * 256 + tid;
        int row = idx >> 6, c = idx & 63;
        const u16* src = hsrc + (size_t)row * rstride + c * 8;
        asm volatile("global_load_dwordx4 %0, %1, off sc0" : "=v"(hv[i]) : "v"(src));
      }
      asm volatile("s_waitcnt vmcnt(8)" ::: "memory");
      __builtin_amdgcn_sched_barrier(0);
      #pragma unroll
      for (int i = 0; i < 8; ++i){
        int ii  = (i + s) & 15;
        int idx = ii * 256 + tid;
        int row = idx >> 6, c = idx & 63;
        *(short8*)(h_lds + row * 512 + ((c ^ (row & 7)) * 8)) = hv[i];
      }
      asm volatile("s_waitcnt vmcnt(0)" ::: "memory");
      __builtin_amdgcn_sched_barrier(0);
      #pragma unroll
      for (int i = 8; i < 16; ++i){
        int ii  = (i + s) & 15;
        int idx = ii * 256 + tid;
        int row = idx >> 6, c = idx & 63;
        *(short8*)(h_lds + row * 512 + ((c ^ (row & 7)) * 8)) = hv[i];
      }
      __syncthreads();

      // ---- MFMA: acc[m][n] = sum_k h[m][k] * W^T[k][n] ----
      f32x16 a1 = {0,0,0,0,0,0,0,0,0,0,0,0,0,0,0,0};
      f32x16 a2 = {0,0,0,0,0,0,0,0,0,0,0,0,0,0,0,0};
      const int m  = wm + (lane & 31);
      const int cb = (lane >> 5);
      #pragma unroll
      for (int kk = 0; kk < 32; ++kk){
        int c = kk * 2 + cb;
        short8 a = *(const short8*)(h_lds + m * 512 + ((c ^ (m & 7)) * 8));
        if (kk & 1) a2 = __builtin_amdgcn_mfma_f32_32x32x16_bf16(a, bq[kk], a2, 0, 0, 0);
        else        a1 = __builtin_amdgcn_mfma_f32_32x32x16_bf16(a, bq[kk], a1, 0, 0, 0);
      }
      #pragma unroll
      for (int r = 0; r < 16; ++r) accv[r] = a1[r] + a2[r];
    }

    // gates to LDS: D[m][n]: n = lane&31(+wn), m = (r&3)+8*(r>>2)+4*(lane>>5) (+wm)
    #pragma unroll
    for (int r = 0; r < 16; ++r){
      int ml = wm + (r & 3) + 8 * (r >> 2) + 4 * (lane >> 5);
      gates_lds[g_of_n][ml][j_of_n] = accv[r];
    }
    __syncthreads();

    // gate math + state update
    short4v hout;
    float hof[4];
    #pragma unroll
    for (int q = 0; q < 4; ++q){
      const int j = gj + q;
      float gi = gates_lds[0][gm][j] + bf2f(xgv[0][q]);
      float gf = gates_lds[1][gm][j] + bf2f(xgv[1][q]);
      float gg = gates_lds[2][gm][j] + bf2f(xgv[2][q]);
      float go = gates_lds[3][gm][j] + bf2f(xgv[3][q]);
      float iv = sigm(gi), fv = sigm(gf), gv = tanhx(gg), ov = sigm(go);
      float c  = fv * cst[q] + iv * gv;
      cst[q]   = c;
      float h  = ov * tanhx(c);
      hof[q]   = h;
      hout[q]  = (short)f2bf(h);
    }

    // publish h via XCD-local L2 stores (fresh addresses every step).
    if (LAYER == 0){
      u16* dst = x1 + ((size_t)t * 64 + gm) * 1024 + dir * 512 + s * 16 + gj;
      st8_l2(dst, hout);
      asm volatile("s_waitcnt vmcnt(0)" ::: "memory");
    } else {
      u16* dst = hexch + ((size_t)t * 2 + dir) * (64 * 512) + gm * 512 + s * 16 + gj;
      st8_l2(dst, hout);
      float4 dv = { hof[0], hof[1], hof[2], hof[3] };
      *(float4*)(dout + ((size_t)gm * 512 + t) * 1024 + dir * 512 + s * 16 + gj) = dv;
      asm volatile("s_waitcnt vmcnt(1)" ::: "memory");   // hexch ack'd; dout may fly
    }
    __syncthreads();                                     // all threads' h stores ack'd
    if (tid == 0){
      int* cp = cntd + it * CNT_STRIDE;
      const int one = 1;
      asm volatile("global_atomic_add %0, %1, off" :: "v"(cp), "v"(one) : "memory");
    }
  }
}

extern "C" void kernel_launch(void* const* d_in, const int* in_sizes, int n_in,
                              void* d_out, int out_size, void* d_ws, size_t ws_size,
                              hipStream_t stream){
  (void)in_sizes; (void)n_in; (void)out_size; (void)ws_size;
  const float* seq = (const float*)d_in[0];
  const float* wih = (const float*)d_in[2];
  const float* whh = (const float*)d_in[3];
  const float* bih = (const float*)d_in[4];
  const float* bhh = (const float*)d_in[5];
  float* out = (float*)d_out;

  // control block (256 KB, memset each launch):
  //   ctrl0 [0..255], ctrl1 [256..511], cnt0 @512 (16384 ints), cnt1 @16896 (16384 ints)
  char* ws    = (char*)d_ws;
  int*  ctrl0 = (int*)ws;
  int*  ctrl1 = ctrl0 + 256;
  int*  cnt0  = ctrl0 + 512;
  int*  cnt1  = cnt0 + 16384;

  u16*  seqb = (u16*)(ws + 262144);                     // 33,554,432 u16 (64 MB)
  u16*  wihb = seqb + (size_t)33554432;                 //  8,388,608
  u16*  whhb = wihb + (size_t)8388608;                  //  4,194,304
  u16*  x1   = whhb + (size_t)4194304;                  // 33,554,432
  u16*  xgb  = x1   + (size_t)33554432;                 // 134,217,728
  u16*  hexb = seqb;   // layer1 t-indexed h exchange [512][2][64][512] aliases seqb
                       // (seqb dead after k_gemm<1>; sizes match: 64 MB)

  hipMemsetAsync(ctrl0, 0, 262144, stream);
  k_cvt<<<32768, 256, 0, stream>>>(seq, seqb, 8388608);
  k_cvt<<<8192,  256, 0, stream>>>(wih, wihb, 2097152);
  k_cvt<<<4096,  256, 0, stream>>>(whh, whhb, 1048576);

  dim3 gg(256, 32);
  // layer 0
  k_gemm<1><<<gg, 256, 0, stream>>>(seqb, wihb, bih, bhh, xgb);
  k_rec<0><<<512, 256, 0, stream>>>(whhb, xgb, x1, hexb, out, ctrl0, cnt0);
  // layer 1
  k_gemm<0><<<gg, 256, 0, stream>>>(x1, wihb + 4194304, bih + 4096, bhh + 4096, xgb);
  k_rec<1><<<512, 256, 0, stream>>>(whhb + 2097152, xgb, x1, hexb, out, ctrl1, cnt1);
}

// Round 17
// 3899.287 us; speedup vs baseline: 3.2023x; 1.2929x over previous
//
#include <hip/hip_runtime.h>
#include <cstdint>

typedef unsigned short u16;
typedef __attribute__((ext_vector_type(8))) short short8;     // 8 x bf16 (4 VGPRs)
typedef __attribute__((ext_vector_type(4))) short short4v;    // 4 x bf16 (2 VGPRs)
typedef __attribute__((ext_vector_type(4))) float f32x4;

// B=64, T=512, H=512, D_IN=1024, L=2, DIRS=2

__device__ __forceinline__ u16 f2bf(float x){
  uint32_t u = __float_as_uint(x);
  u += 0x7fffu + ((u >> 16) & 1u);          // RNE
  return (u16)(u >> 16);
}
__device__ __forceinline__ float bf2f(u16 b){ return __uint_as_float(((uint32_t)b) << 16); }
__device__ __forceinline__ float sigm(float x){ return 1.f / (1.f + __expf(-x)); }
__device__ __forceinline__ float tanhx(float x){
  float xc = fminf(fmaxf(x, -30.f), 30.f);
  float e  = __expf(-2.f * xc);
  return (1.f - e) / (1.f + e);
}

// XCD-local coherent store (bypass L1, lands in the XCD's L2).
// R4/R6 lessons: sc0 LOADS are L1-cacheable -> never poll with plain loads;
// atomics execute at L2+ (no L1 staleness) -> poll with atomics (R7 proven).
__device__ __forceinline__ void st4_l2(u16* p, uint32_t v){
  asm volatile("global_store_dword %0, %1, off sc0" :: "v"(p), "v"(v) : "memory");
}

#define CNT_STRIDE 16   // ints: one 64B sector per step counter

// ---------------- fp32 -> bf16 convert ----------------
__global__ void k_cvt(const float* __restrict__ in, u16* __restrict__ out, int n4){
  int i = blockIdx.x * blockDim.x + threadIdx.x;
  if (i >= n4) return;
  float4 v = ((const float4*)in)[i];
  ushort4 o;
  o.x = f2bf(v.x); o.y = f2bf(v.y); o.z = f2bf(v.z); o.w = f2bf(v.w);
  ((ushort4*)out)[i] = o;
}

// ---------------- input GEMM: xg = A @ W^T + bias, bf16 in, bf16 out ----------------
template<int LAYER0>
__global__ __launch_bounds__(256) void k_gemm(
    const u16* __restrict__ A, const u16* __restrict__ W,
    const float* __restrict__ bih, const float* __restrict__ bhh,
    u16* __restrict__ xg)
{
  __shared__ u16 Al[128 * 64];
  __shared__ u16 Bl[128 * 64];
  const int tid  = threadIdx.x;
  const int bm   = blockIdx.x, bn = blockIdx.y;
  const int w    = tid >> 6, lane = tid & 63;
  const int wm   = (w >> 1) * 64;
  const int wn   = (w & 1) * 64;
  f32x4 acc[4][4] = {};

  for (int kt = 0; kt < 1024; kt += 64){
    __syncthreads();
    #pragma unroll
    for (int it = 0; it < 4; ++it){
      int idx = tid + it * 256;
      int row = idx >> 3, c = idx & 7;
      size_t aoff;
      int m = bm * 128 + row;
      if (LAYER0) aoff = ((size_t)(m & 63) * 512 + (m >> 6)) * 1024;
      else        aoff = (size_t)m * 1024;
      short8 va = *(const short8*)(A + aoff + kt + c * 8);
      *(short8*)(Al + row * 64 + ((c ^ (row & 7)) * 8)) = va;
      int n = bn * 128 + row;
      short8 vb = *(const short8*)(W + (size_t)n * 1024 + kt + c * 8);
      *(short8*)(Bl + row * 64 + ((c ^ (row & 7)) * 8)) = vb;
    }
    __syncthreads();
    const int kg = lane >> 4;
    #pragma unroll
    for (int kk = 0; kk < 2; ++kk){
      short8 a[4], b[4];
      #pragma unroll
      for (int i = 0; i < 4; ++i){
        int rA = wm + i * 16 + (lane & 15);
        int cA = kk * 4 + kg;
        a[i] = *(const short8*)(Al + rA * 64 + ((cA ^ (rA & 7)) * 8));
        int rB = wn + i * 16 + (lane & 15);
        b[i] = *(const short8*)(Bl + rB * 64 + ((cA ^ (rB & 7)) * 8));
      }
      #pragma unroll
      for (int i = 0; i < 4; ++i)
        #pragma unroll
        for (int j = 0; j < 4; ++j)
          acc[i][j] = __builtin_amdgcn_mfma_f32_16x16x32_bf16(a[i], b[j], acc[i][j], 0, 0, 0);
    }
  }
  #pragma unroll
  for (int i = 0; i < 4; ++i){
    #pragma unroll
    for (int j = 0; j < 4; ++j){
      int n_g = bn * 128 + wn + j * 16 + (lane & 15);
      float bias = bih[n_g] + bhh[n_g];
      #pragma unroll
      for (int q = 0; q < 4; ++q){
        int m_g = bm * 128 + wm + i * 16 + (lane >> 4) * 4 + q;
        xg[(size_t)m_g * 4096 + n_g] = f2bf(acc[i][j][q] + bias);
      }
    }
  }
}

// ---------------- persistent LSTM recurrence: 4 XCD groups (dir x batch-half) ----------------
// R17: batch samples are independent -> split batch 64 into two halves. Group grp =
// dir*2+bh owns 32 batch rows x 2048 gate cols, 32 WGs on ONE XCD (election, R3).
// Per WG: M=32, N=64 (wave w = gate w, 16 cols), K=512; mfma 16x16x32 (k_gemm-verified
// fragment layout). Staged h per step = 32KB (HALF of R16), staggered walk (R16),
// t-indexed atomic-counter sync at fan-in 32 (R7).
template<int LAYER>
__global__ __launch_bounds__(256, 1) void k_rec(
    const u16* __restrict__ whh,   // (2, 2048, 512) bf16, this layer
    const u16* __restrict__ xg,    // (32768, 4096) bf16
    u16*  __restrict__ x1,         // (32768, 1024) bf16: layer0 output + layer0 h exchange
    u16*  __restrict__ hexch,      // [512 t][4 grp][32][512] bf16: layer1 h exchange
    float* __restrict__ dout,      // (64, 512, 1024) fp32 final output
    int*  __restrict__ ctrl,       // election block: cnt[8*16], grpmap@128..135, slot@136
    int*  __restrict__ cnt)        // step counters: [grp][512][CNT_STRIDE], zeroed
{
  const int tid = threadIdx.x;
  __shared__ int sh_rank, sh_grp;

  if (tid == 0){
    uint32_t xcd;
    asm volatile("s_getreg_b32 %0, hwreg(HW_REG_XCC_ID)" : "=s"(xcd));
    xcd &= 7;
    int rank = __hip_atomic_fetch_add(ctrl + xcd * 16, 1, __ATOMIC_RELAXED, __HIP_MEMORY_SCOPE_AGENT);
    int dm;
    if (rank == 0){
      int slot = __hip_atomic_fetch_add(ctrl + 136, 1, __ATOMIC_RELAXED, __HIP_MEMORY_SCOPE_AGENT);
      dm = slot + 1;
      __hip_atomic_store(ctrl + 128 + xcd, dm, __ATOMIC_RELEASE, __HIP_MEMORY_SCOPE_AGENT);
    } else {
      do {
        dm = __hip_atomic_load(ctrl + 128 + xcd, __ATOMIC_ACQUIRE, __HIP_MEMORY_SCOPE_AGENT);
      } while (dm == 0);
    }
    sh_rank = rank; sh_grp = dm - 1;
  }
  __syncthreads();
  const int s   = sh_rank;           // worker slice 0..31 (16 h-cols each)
  const int grp = sh_grp;            // 0..3 = dir*2 + bh
  if (s >= 32 || grp >= 4) return;   // not a worker
  const int dir = grp >> 1, bh = grp & 1;

  const int w    = tid >> 6, lane = tid & 63;   // wave w = gate w
  const int aj   = lane & 15;                   // col-within-16 / row-within-16
  const int kg   = lane >> 4;                   // k-quarter 0..3

  // LDS oversized to force 1 WG/CU (2x83KB > 160KB). Arrays genuinely used -> not DCE'd.
  __shared__ u16  h_lds[64 * 512];              // use rows 0..31 (32KB of 64KB)
  __shared__ float gates_lds[4][64][17];        // use rows 0..31

  // W_hh B-frags (k_gemm-verified 16x16x32 layout): lane holds B[n=aj][k=kk*32+kg*8..+8]
  // for gate w: row g*512 + s*16 + aj of W (2048x512 row-major).
  const u16* wd = whh + (size_t)dir * (2048 * 512);
  short8 bq[16];
  {
    const size_t rbase = (size_t)(w * 512 + s * 16 + aj) * 512;
    #pragma unroll
    for (int kk = 0; kk < 16; ++kk)
      bq[kk] = *(const short8*)(wd + rbase + kk * 32 + kg * 8);
  }

  float cst[2] = {0.f, 0.f};
  const int tstep = dir ? -1 : 1;
  const int t0    = dir ? 511 : 0;
  int* const cntd = cnt + (size_t)grp * 512 * CNT_STRIDE;

  // gate-math geometry: thread owns local batch row gm (0..31), cols j0, j0+1
  const int gm = tid >> 3;
  const int j0 = (tid & 7) * 2;
  const int b  = bh * 32 + gm;        // global batch row

  for (int it = 0; it < 512; ++it){
    const int t = t0 + tstep * it;

    // xg prefetch: 4 x ushort2 (oldest in vmcnt queue; drain under poll/stage waits)
    const size_t xb0 = ((size_t)t * 64 + b) * 4096 + (size_t)dir * 2048 + s * 16 + j0;
    ushort2 xgv[4];
    #pragma unroll
    for (int g = 0; g < 4; ++g) xgv[g] = *(const ushort2*)(xg + xb0 + g * 512);

    f32x4 acc0 = {0.f,0.f,0.f,0.f}, acc1 = {0.f,0.f,0.f,0.f};

    if (it > 0){
      const int tprev = t - tstep;
      // ---- wait for all 32 producers of step it-1 (L2-local atomic poll) ----
      if (tid == 0){
        int* cp = cntd + (it - 1) * CNT_STRIDE;
        const int zero = 0;
        while (true){
          int old;
          asm volatile("global_atomic_add %0, %1, %2, off sc0\n\ts_waitcnt vmcnt(0)"
                       : "=v"(old) : "v"(cp), "v"(zero) : "memory");
          if (old >= 32) break;
          __builtin_amdgcn_s_sleep(1);
        }
      }
      __syncthreads();

      // ---- stage h(t-1) for OUR batch half (32 x 512 bf16 = 32KB), staggered walk ----
      const u16* hsrc;
      size_t rstride;
      if (LAYER == 0){ hsrc = x1 + ((size_t)tprev * 64 + bh * 32) * 1024 + dir * 512; rstride = 1024; }
      else           { hsrc = hexch + ((size_t)tprev * 4 + grp) * (32 * 512);          rstride = 512; }

      short8 hv[8];
      #pragma unroll
      for (int i = 0; i < 8; ++i){
        int ii  = (i + s) & 7;             // staggered walk (R16, +6%)
        int idx = ii * 256 + tid;
        int row = idx >> 6, c = idx & 63;
        const u16* src = hsrc + (size_t)row * rstride + c * 8;
        asm volatile("global_load_dwordx4 %0, %1, off sc0" : "=v"(hv[i]) : "v"(src));
      }
      asm volatile("s_waitcnt vmcnt(4)" ::: "memory");   // 4 xg oldest -> hv[0..3] ready
      __builtin_amdgcn_sched_barrier(0);
      #pragma unroll
      for (int i = 0; i < 4; ++i){
        int ii  = (i + s) & 7;
        int idx = ii * 256 + tid;
        int row = idx >> 6, c = idx & 63;
        *(short8*)(h_lds + row * 512 + ((c ^ (row & 7)) * 8)) = hv[i];
      }
      asm volatile("s_waitcnt vmcnt(0)" ::: "memory");
      __builtin_amdgcn_sched_barrier(0);
      #pragma unroll
      for (int i = 4; i < 8; ++i){
        int ii  = (i + s) & 7;
        int idx = ii * 256 + tid;
        int row = idx >> 6, c = idx & 63;
        *(short8*)(h_lds + row * 512 + ((c ^ (row & 7)) * 8)) = hv[i];
      }
      __syncthreads();

      // ---- MFMA: two 16x16 tiles (local rows 0..15, 16..31), K=512 ----
      #pragma unroll
      for (int kk = 0; kk < 16; ++kk){
        int c = kk * 4 + kg;
        short8 a0 = *(const short8*)(h_lds + aj * 512 + ((c ^ (aj & 7)) * 8));
        int r1 = 16 + aj;
        short8 a1 = *(const short8*)(h_lds + r1 * 512 + ((c ^ (r1 & 7)) * 8));
        acc0 = __builtin_amdgcn_mfma_f32_16x16x32_bf16(a0, bq[kk], acc0, 0, 0, 0);
        acc1 = __builtin_amdgcn_mfma_f32_16x16x32_bf16(a1, bq[kk], acc1, 0, 0, 0);
      }
    }

    // gates to LDS: D[m][n]: n = aj, m = kg*4 + q (tile0), 16 + kg*4 + q (tile1)
    #pragma unroll
    for (int q = 0; q < 4; ++q){
      gates_lds[w][kg * 4 + q][aj]      = acc0[q];
      gates_lds[w][16 + kg * 4 + q][aj] = acc1[q];
    }
    __syncthreads();

    // gate math + state update: thread owns (gm, j0) and (gm, j0+1)
    uint32_t hpack;
    float hof[2];
    #pragma unroll
    for (int q = 0; q < 2; ++q){
      const int j = j0 + q;
      float gi = gates_lds[0][gm][j] + bf2f(((const u16*)&xgv[0])[q]);
      float gf = gates_lds[1][gm][j] + bf2f(((const u16*)&xgv[1])[q]);
      float gg = gates_lds[2][gm][j] + bf2f(((const u16*)&xgv[2])[q]);
      float go = gates_lds[3][gm][j] + bf2f(((const u16*)&xgv[3])[q]);
      float iv = sigm(gi), fv = sigm(gf), gv = tanhx(gg), ov = sigm(go);
      float c  = fv * cst[q] + iv * gv;
      cst[q]   = c;
      float h  = ov * tanhx(c);
      hof[q]   = h;
      if (q == 0) hpack = (uint32_t)f2bf(h);
      else        hpack |= ((uint32_t)f2bf(h)) << 16;
    }

    // publish h via XCD-local L2 stores (fresh addresses every step)
    if (LAYER == 0){
      u16* dst = x1 + ((size_t)t * 64 + b) * 1024 + dir * 512 + s * 16 + j0;
      st4_l2(dst, hpack);
      asm volatile("s_waitcnt vmcnt(0)" ::: "memory");
    } else {
      u16* dst = hexch + ((size_t)t * 4 + grp) * (32 * 512) + gm * 512 + s * 16 + j0;
      st4_l2(dst, hpack);
      float2 dv = { hof[0], hof[1] };
      *(float2*)(dout + ((size_t)b * 512 + t) * 1024 + dir * 512 + s * 16 + j0) = dv;
      asm volatile("s_waitcnt vmcnt(1)" ::: "memory");   // hexch ack'd; dout may fly
    }
    __syncthreads();                                     // all threads' h stores ack'd
    if (tid == 0){
      int* cp = cntd + it * CNT_STRIDE;
      const int one = 1;
      asm volatile("global_atomic_add %0, %1, off" :: "v"(cp), "v"(one) : "memory");
    }
  }
}

extern "C" void kernel_launch(void* const* d_in, const int* in_sizes, int n_in,
                              void* d_out, int out_size, void* d_ws, size_t ws_size,
                              hipStream_t stream){
  (void)in_sizes; (void)n_in; (void)out_size; (void)ws_size;
  const float* seq = (const float*)d_in[0];
  const float* wih = (const float*)d_in[2];
  const float* whh = (const float*)d_in[3];
  const float* bih = (const float*)d_in[4];
  const float* bhh = (const float*)d_in[5];
  float* out = (float*)d_out;

  // control block (memset each launch): ctrl0 @0 (256 ints), ctrl1 @256,
  // cnt0 @512 (4 grp x 512 x 16 = 32768 ints), cnt1 @33280 (32768 ints)
  char* ws    = (char*)d_ws;
  int*  ctrl0 = (int*)ws;
  int*  ctrl1 = ctrl0 + 256;
  int*  cnt0  = ctrl0 + 512;
  int*  cnt1  = cnt0 + 32768;

  u16*  seqb = (u16*)(ws + 524288);                     // 33,554,432 u16 (64 MB)
  u16*  wihb = seqb + (size_t)33554432;                 //  8,388,608
  u16*  whhb = wihb + (size_t)8388608;                  //  4,194,304
  u16*  x1   = whhb + (size_t)4194304;                  // 33,554,432
  u16*  xgb  = x1   + (size_t)33554432;                 // 134,217,728
  u16*  hexb = seqb;   // layer1 h exchange [512][4][32][512] aliases seqb
                       // (seqb dead after k_gemm<1>; sizes match: 64 MB)

  hipMemsetAsync(ctrl0, 0, 266240, stream);
  k_cvt<<<32768, 256, 0, stream>>>(seq, seqb, 8388608);
  k_cvt<<<8192,  256, 0, stream>>>(wih, wihb, 2097152);
  k_cvt<<<4096,  256, 0, stream>>>(whh, whhb, 1048576);

  dim3 gg(256, 32);
  // layer 0
  k_gemm<1><<<gg, 256, 0, stream>>>(seqb, wihb, bih, bhh, xgb);
  k_rec<0><<<512, 256, 0, stream>>>(whhb, xgb, x1, hexb, out, ctrl0, cnt0);
  // layer 1
  k_gemm<0><<<gg, 256, 0, stream>>>(x1, wihb + 4194304, bih + 4096, bhh + 4096, xgb);
  k_rec<1><<<512, 256, 0, stream>>>(whhb + 2097152, xgb, x1, hexb, out, ctrl1, cnt1);
}

// Round 18
// 3277.581 us; speedup vs baseline: 3.8097x; 1.1897x over previous
//
#include <hip/hip_runtime.h>
#include <cstdint>

typedef unsigned short u16;
typedef __attribute__((ext_vector_type(8))) short short8;     // 8 x bf16 (4 VGPRs)
typedef __attribute__((ext_vector_type(4))) float f32x4;

// B=64, T=512, H=512, D_IN=1024, L=2, DIRS=2

__device__ __forceinline__ u16 f2bf(float x){
  uint32_t u = __float_as_uint(x);
  u += 0x7fffu + ((u >> 16) & 1u);          // RNE
  return (u16)(u >> 16);
}
__device__ __forceinline__ float bf2f(u16 b){ return __uint_as_float(((uint32_t)b) << 16); }
__device__ __forceinline__ float sigm(float x){ return 1.f / (1.f + __expf(-x)); }
__device__ __forceinline__ float tanhx(float x){
  float xc = fminf(fmaxf(x, -30.f), 30.f);
  float e  = __expf(-2.f * xc);
  return (1.f - e) / (1.f + e);
}

// XCD-local coherent store (bypass L1, lands in the XCD's L2).
// R4/R6 lessons: sc0 LOADS are L1-cacheable -> never poll with plain loads;
// atomics execute at L2+ (no L1 staleness) -> poll with atomics (R7 proven).
__device__ __forceinline__ void st2_l2(u16* p, uint32_t v){
  asm volatile("global_store_short %0, %1, off sc0" :: "v"(p), "v"(v) : "memory");
}

#define CNT_STRIDE 16   // ints: one 64B sector per step counter

// ---------------- fp32 -> bf16 convert ----------------
__global__ void k_cvt(const float* __restrict__ in, u16* __restrict__ out, int n4){
  int i = blockIdx.x * blockDim.x + threadIdx.x;
  if (i >= n4) return;
  float4 v = ((const float4*)in)[i];
  ushort4 o;
  o.x = f2bf(v.x); o.y = f2bf(v.y); o.z = f2bf(v.z); o.w = f2bf(v.w);
  ((ushort4*)out)[i] = o;
}

// ---------------- input GEMM: xg = A @ W^T + bias, bf16 in, bf16 out ----------------
template<int LAYER0>
__global__ __launch_bounds__(256) void k_gemm(
    const u16* __restrict__ A, const u16* __restrict__ W,
    const float* __restrict__ bih, const float* __restrict__ bhh,
    u16* __restrict__ xg)
{
  __shared__ u16 Al[128 * 64];
  __shared__ u16 Bl[128 * 64];
  const int tid  = threadIdx.x;
  const int bm   = blockIdx.x, bn = blockIdx.y;
  const int w    = tid >> 6, lane = tid & 63;
  const int wm   = (w >> 1) * 64;
  const int wn   = (w & 1) * 64;
  f32x4 acc[4][4] = {};

  for (int kt = 0; kt < 1024; kt += 64){
    __syncthreads();
    #pragma unroll
    for (int it = 0; it < 4; ++it){
      int idx = tid + it * 256;
      int row = idx >> 3, c = idx & 7;
      size_t aoff;
      int m = bm * 128 + row;
      if (LAYER0) aoff = ((size_t)(m & 63) * 512 + (m >> 6)) * 1024;
      else        aoff = (size_t)m * 1024;
      short8 va = *(const short8*)(A + aoff + kt + c * 8);
      *(short8*)(Al + row * 64 + ((c ^ (row & 7)) * 8)) = va;
      int n = bn * 128 + row;
      short8 vb = *(const short8*)(W + (size_t)n * 1024 + kt + c * 8);
      *(short8*)(Bl + row * 64 + ((c ^ (row & 7)) * 8)) = vb;
    }
    __syncthreads();
    const int kg = lane >> 4;
    #pragma unroll
    for (int kk = 0; kk < 2; ++kk){
      short8 a[4], b[4];
      #pragma unroll
      for (int i = 0; i < 4; ++i){
        int rA = wm + i * 16 + (lane & 15);
        int cA = kk * 4 + kg;
        a[i] = *(const short8*)(Al + rA * 64 + ((cA ^ (rA & 7)) * 8));
        int rB = wn + i * 16 + (lane & 15);
        b[i] = *(const short8*)(Bl + rB * 64 + ((cA ^ (rB & 7)) * 8));
      }
      #pragma unroll
      for (int i = 0; i < 4; ++i)
        #pragma unroll
        for (int j = 0; j < 4; ++j)
          acc[i][j] = __builtin_amdgcn_mfma_f32_16x16x32_bf16(a[i], b[j], acc[i][j], 0, 0, 0);
    }
  }
  #pragma unroll
  for (int i = 0; i < 4; ++i){
    #pragma unroll
    for (int j = 0; j < 4; ++j){
      int n_g = bn * 128 + wn + j * 16 + (lane & 15);
      float bias = bih[n_g] + bhh[n_g];
      #pragma unroll
      for (int q = 0; q < 4; ++q){
        int m_g = bm * 128 + wm + i * 16 + (lane >> 4) * 4 + q;
        xg[(size_t)m_g * 4096 + n_g] = f2bf(acc[i][j][q] + bias);
      }
    }
  }
}

// ---------------- persistent LSTM recurrence: 8 XCD groups (dir x batch-quarter) ----------------
// R18: grp = dir*4 + bq; each group owns 16 batch rows x 2048 gate cols on ONE XCD
// (32 WGs, election R3). Per WG: M=16, N=64 (wave w = gate, 16 cols), K=512 via
// mfma 16x16x32 (k_gemm-verified layout). Staged h/step = 16KB (half of R17),
// staggered walk (R16), t-indexed atomic-counter sync fan-in 32 (R7).
template<int LAYER>
__global__ __launch_bounds__(256, 1) void k_rec(
    const u16* __restrict__ whh,   // (2, 2048, 512) bf16, this layer
    const u16* __restrict__ xg,    // (32768, 4096) bf16
    u16*  __restrict__ x1,         // (32768, 1024) bf16: layer0 output + layer0 h exchange
    u16*  __restrict__ hexch,      // [512 t][8 grp][16][512] bf16: layer1 h exchange
    float* __restrict__ dout,      // (64, 512, 1024) fp32 final output
    int*  __restrict__ ctrl,       // election block: cnt[8*16], grpmap@128..135, slot@136
    int*  __restrict__ cnt)        // step counters: [grp][512][CNT_STRIDE], zeroed
{
  const int tid = threadIdx.x;
  __shared__ int sh_rank, sh_grp;

  if (tid == 0){
    uint32_t xcd;
    asm volatile("s_getreg_b32 %0, hwreg(HW_REG_XCC_ID)" : "=s"(xcd));
    xcd &= 7;
    int rank = __hip_atomic_fetch_add(ctrl + xcd * 16, 1, __ATOMIC_RELAXED, __HIP_MEMORY_SCOPE_AGENT);
    int dm;
    if (rank == 0){
      int slot = __hip_atomic_fetch_add(ctrl + 136, 1, __ATOMIC_RELAXED, __HIP_MEMORY_SCOPE_AGENT);
      dm = slot + 1;
      __hip_atomic_store(ctrl + 128 + xcd, dm, __ATOMIC_RELEASE, __HIP_MEMORY_SCOPE_AGENT);
    } else {
      do {
        dm = __hip_atomic_load(ctrl + 128 + xcd, __ATOMIC_ACQUIRE, __HIP_MEMORY_SCOPE_AGENT);
      } while (dm == 0);
    }
    sh_rank = rank; sh_grp = dm - 1;
  }
  __syncthreads();
  const int s   = sh_rank;           // worker slice 0..31 (16 h-cols each)
  const int grp = sh_grp;            // 0..7 = dir*4 + bq
  if (s >= 32 || grp >= 8) return;   // not a worker
  const int dir = grp >> 2, bq = grp & 3;

  const int w    = tid >> 6, lane = tid & 63;   // wave w = gate w
  const int aj   = lane & 15;                   // A row / B col / D col
  const int kg   = lane >> 4;                   // k-quarter 0..3

  // LDS oversized to force 1 WG/CU (2x81KB > 160KB). Arrays genuinely used -> no DCE.
  __shared__ u16  h_lds[64 * 512];              // use rows 0..15 (16KB of 64KB)
  __shared__ float gates_lds[4][64][17];        // use rows 0..15

  // W_hh B-frags (16x16x32): lane holds B[n=aj][k = kk*32 + kg*8 .. +8] for gate w,
  // i.e. W row w*512 + s*16 + aj of (2048x512).
  const u16* wd = whh + (size_t)dir * (2048 * 512);
  short8 bq_[16];
  {
    const size_t rbase = (size_t)(w * 512 + s * 16 + aj) * 512;
    #pragma unroll
    for (int kk = 0; kk < 16; ++kk)
      bq_[kk] = *(const short8*)(wd + rbase + kk * 32 + kg * 8);
  }

  float cst = 0.f;
  const int tstep = dir ? -1 : 1;
  const int t0    = dir ? 511 : 0;
  int* const cntd = cnt + (size_t)grp * 512 * CNT_STRIDE;

  // gate-math geometry: thread owns local batch row gm (0..15), col j (0..15)
  const int gm = tid >> 4;
  const int j  = tid & 15;
  const int b  = bq * 16 + gm;        // global batch row

  for (int it = 0; it < 512; ++it){
    const int t = t0 + tstep * it;

    // xg prefetch: 4 scalar u16 (oldest in vmcnt queue; drain under poll/stage waits)
    const size_t xb0 = ((size_t)t * 64 + b) * 4096 + (size_t)dir * 2048 + s * 16 + j;
    u16 xgv[4];
    #pragma unroll
    for (int g = 0; g < 4; ++g) xgv[g] = xg[xb0 + g * 512];

    f32x4 accA = {0.f,0.f,0.f,0.f}, accB = {0.f,0.f,0.f,0.f};

    if (it > 0){
      const int tprev = t - tstep;
      // ---- wait for all 32 producers of step it-1 (L2-local atomic poll) ----
      if (tid == 0){
        int* cp = cntd + (it - 1) * CNT_STRIDE;
        const int zero = 0;
        while (true){
          int old;
          asm volatile("global_atomic_add %0, %1, %2, off sc0\n\ts_waitcnt vmcnt(0)"
                       : "=v"(old) : "v"(cp), "v"(zero) : "memory");
          if (old >= 32) break;
          __builtin_amdgcn_s_sleep(1);
        }
      }
      __syncthreads();

      // ---- stage h(t-1) for OUR batch quarter (16 x 512 bf16 = 16KB), staggered ----
      const u16* hsrc;
      size_t rstride;
      if (LAYER == 0){ hsrc = x1 + ((size_t)tprev * 64 + bq * 16) * 1024 + dir * 512; rstride = 1024; }
      else           { hsrc = hexch + ((size_t)tprev * 8 + grp) * (16 * 512);          rstride = 512; }

      short8 hv[4];
      #pragma unroll
      for (int i = 0; i < 4; ++i){
        int ii  = (i + s) & 3;             // staggered walk (R16, +6%)
        int idx = ii * 256 + tid;
        int row = idx >> 6, c = idx & 63;
        const u16* src = hsrc + (size_t)row * rstride + c * 8;
        asm volatile("global_load_dwordx4 %0, %1, off sc0" : "=v"(hv[i]) : "v"(src));
      }
      asm volatile("s_waitcnt vmcnt(2)" ::: "memory");   // 4 xg + hv[0..1] drained
      __builtin_amdgcn_sched_barrier(0);
      #pragma unroll
      for (int i = 0; i < 2; ++i){
        int ii  = (i + s) & 3;
        int idx = ii * 256 + tid;
        int row = idx >> 6, c = idx & 63;
        *(short8*)(h_lds + row * 512 + ((c ^ (row & 7)) * 8)) = hv[i];
      }
      asm volatile("s_waitcnt vmcnt(0)" ::: "memory");
      __builtin_amdgcn_sched_barrier(0);
      #pragma unroll
      for (int i = 2; i < 4; ++i){
        int ii  = (i + s) & 3;
        int idx = ii * 256 + tid;
        int row = idx >> 6, c = idx & 63;
        *(short8*)(h_lds + row * 512 + ((c ^ (row & 7)) * 8)) = hv[i];
      }
      __syncthreads();

      // ---- MFMA: one 16x16 tile, K=512, two interleaved accumulators ----
      #pragma unroll
      for (int kk = 0; kk < 16; ++kk){
        int c = kk * 4 + kg;
        short8 a = *(const short8*)(h_lds + aj * 512 + ((c ^ (aj & 7)) * 8));
        if (kk & 1) accB = __builtin_amdgcn_mfma_f32_16x16x32_bf16(a, bq_[kk], accB, 0, 0, 0);
        else        accA = __builtin_amdgcn_mfma_f32_16x16x32_bf16(a, bq_[kk], accA, 0, 0, 0);
      }
      #pragma unroll
      for (int q = 0; q < 4; ++q) accA[q] += accB[q];
    }

    // gates to LDS: D[m][n]: n = aj, m = kg*4 + q
    #pragma unroll
    for (int q = 0; q < 4; ++q)
      gates_lds[w][kg * 4 + q][aj] = accA[q];
    __syncthreads();

    // gate math + state update: thread owns (gm, j)
    float gi = gates_lds[0][gm][j] + bf2f(xgv[0]);
    float gf = gates_lds[1][gm][j] + bf2f(xgv[1]);
    float gg = gates_lds[2][gm][j] + bf2f(xgv[2]);
    float go = gates_lds[3][gm][j] + bf2f(xgv[3]);
    float iv = sigm(gi), fv = sigm(gf), gv = tanhx(gg), ov = sigm(go);
    float c  = fv * cst + iv * gv;
    cst      = c;
    float h  = ov * tanhx(c);
    uint32_t hb16 = (uint32_t)f2bf(h);

    // publish h via XCD-local L2 stores (fresh addresses every step)
    if (LAYER == 0){
      u16* dst = x1 + ((size_t)t * 64 + b) * 1024 + dir * 512 + s * 16 + j;
      st2_l2(dst, hb16);
      asm volatile("s_waitcnt vmcnt(0)" ::: "memory");
    } else {
      u16* dst = hexch + ((size_t)t * 8 + grp) * (16 * 512) + gm * 512 + s * 16 + j;
      st2_l2(dst, hb16);
      dout[((size_t)b * 512 + t) * 1024 + dir * 512 + s * 16 + j] = h;
      asm volatile("s_waitcnt vmcnt(1)" ::: "memory");   // hexch ack'd; dout may fly
    }
    __syncthreads();                                     // all threads' h stores ack'd
    if (tid == 0){
      int* cp = cntd + it * CNT_STRIDE;
      const int one = 1;
      asm volatile("global_atomic_add %0, %1, off" :: "v"(cp), "v"(one) : "memory");
    }
  }
}

extern "C" void kernel_launch(void* const* d_in, const int* in_sizes, int n_in,
                              void* d_out, int out_size, void* d_ws, size_t ws_size,
                              hipStream_t stream){
  (void)in_sizes; (void)n_in; (void)out_size; (void)ws_size;
  const float* seq = (const float*)d_in[0];
  const float* wih = (const float*)d_in[2];
  const float* whh = (const float*)d_in[3];
  const float* bih = (const float*)d_in[4];
  const float* bhh = (const float*)d_in[5];
  float* out = (float*)d_out;

  // control block (memset each launch): ctrl0 @0 (256 ints), ctrl1 @256,
  // cnt0 @512 (8 grp x 512 x 16 = 65536 ints), cnt1 @66048 (65536 ints)
  char* ws    = (char*)d_ws;
  int*  ctrl0 = (int*)ws;
  int*  ctrl1 = ctrl0 + 256;
  int*  cnt0  = ctrl0 + 512;
  int*  cnt1  = cnt0 + 65536;

  u16*  seqb = (u16*)(ws + 786432);                     // 33,554,432 u16 (64 MB)
  u16*  wihb = seqb + (size_t)33554432;                 //  8,388,608
  u16*  whhb = wihb + (size_t)8388608;                  //  4,194,304
  u16*  x1   = whhb + (size_t)4194304;                  // 33,554,432
  u16*  xgb  = x1   + (size_t)33554432;                 // 134,217,728
  u16*  hexb = seqb;   // layer1 h exchange [512][8][16][512] aliases seqb
                       // (seqb dead after k_gemm<1>; sizes match: 64 MB exactly)

  hipMemsetAsync(ctrl0, 0, 526336, stream);
  k_cvt<<<32768, 256, 0, stream>>>(seq, seqb, 8388608);
  k_cvt<<<8192,  256, 0, stream>>>(wih, wihb, 2097152);
  k_cvt<<<4096,  256, 0, stream>>>(whh, whhb, 1048576);

  dim3 gg(256, 32);
  // layer 0
  k_gemm<1><<<gg, 256, 0, stream>>>(seqb, wihb, bih, bhh, xgb);
  k_rec<0><<<512, 256, 0, stream>>>(whhb, xgb, x1, hexb, out, ctrl0, cnt0);
  // layer 1
  k_gemm<0><<<gg, 256, 0, stream>>>(x1, wihb + 4194304, bih + 4096, bhh + 4096, xgb);
  k_rec<1><<<512, 256, 0, stream>>>(whhb + 2097152, xgb, x1, hexb, out, ctrl1, cnt1);
}